// Round 4
// baseline (367.288 us; speedup 1.0000x reference)
//
#include <hip/hip_runtime.h>
#include <math.h>

#define BATCH 2
#define SLEN 2048
#define DM 1024
#define NH 16
#define DK 64

typedef __attribute__((ext_vector_type(8))) __bf16 bf16x8;
typedef __attribute__((ext_vector_type(4))) float f32x4;

__device__ __forceinline__ unsigned short f2bf(float x) {  // round-nearest
  unsigned u = __builtin_bit_cast(unsigned, x);
  unsigned r = (u + 0x7fffu + ((u >> 16) & 1u)) >> 16;
  return (unsigned short)r;
}
// cheap truncation split: x ~= hi + lo to ~2^-16 relative
__device__ __forceinline__ void splitbf(float x, unsigned short& h,
                                        unsigned short& l) {
  unsigned u = __builtin_bit_cast(unsigned, x);
  h = (unsigned short)(u >> 16);
  float hf = __builtin_bit_cast(float, u & 0xffff0000u);
  l = (unsigned short)(__builtin_bit_cast(unsigned, x - hf) >> 16);
}

// async global->LDS, 16 B per lane
__device__ __forceinline__ void gld16(const unsigned short* g,
                                      unsigned short* l) {
  __builtin_amdgcn_global_load_lds(
      (const __attribute__((address_space(1))) void*)g,
      (__attribute__((address_space(3))) void*)l, 16, 0, 0);
}

// ---------------------------------------------------------------------------
// Weight transpose+split -> Wt[n][packed k], 64-u16 k-blocks [hi32|lo32],
// 16-B chunks XOR-swizzled with key (n&7).
// ---------------------------------------------------------------------------
__global__ __launch_bounds__(256)
void convert_w(const float* __restrict__ Wq, const float* __restrict__ Wk,
               const float* __restrict__ Wv, unsigned short* __restrict__ Wqt,
               unsigned short* __restrict__ Wkt,
               unsigned short* __restrict__ Wvt) {
  const int kb = blockIdx.x, h = blockIdx.y, z = blockIdx.z;
  const float* W = (z == 0 ? Wq : z == 1 ? Wk : Wv) +
                   ((size_t)h * DM + kb * 64) * DK;
  unsigned short* D = (z == 0 ? Wqt : z == 1 ? Wkt : Wvt);

  __shared__ float T[64][65];
  const int tid = threadIdx.x;
  {
    int r = tid >> 2, c0 = (tid & 3) * 16;
#pragma unroll
    for (int i = 0; i < 4; ++i) {
      float4 f = *(const float4*)(W + (size_t)r * DK + c0 + i * 4);
      T[r][c0 + i * 4 + 0] = f.x;
      T[r][c0 + i * 4 + 1] = f.y;
      T[r][c0 + i * 4 + 2] = f.z;
      T[r][c0 + i * 4 + 3] = f.w;
    }
  }
  __syncthreads();
  int j = tid >> 2, p = tid & 3;
  int n = h * 64 + j;
  int kloc = p * 16;
  unsigned short hi[16], lo[16];
#pragma unroll
  for (int i = 0; i < 16; ++i) splitbf(T[kloc + i][j], hi[i], lo[i]);
  int kglob = kb * 64 + kloc;
  int blk = kglob >> 5;
  int c0 = (kglob & 31) >> 3;
  int key = n & 7;
  unsigned short* rowp = D + (size_t)n * 2048 + blk * 64;
  uint4 u0, u1;
  u0.x = (unsigned)hi[0] | ((unsigned)hi[1] << 16);
  u0.y = (unsigned)hi[2] | ((unsigned)hi[3] << 16);
  u0.z = (unsigned)hi[4] | ((unsigned)hi[5] << 16);
  u0.w = (unsigned)hi[6] | ((unsigned)hi[7] << 16);
  u1.x = (unsigned)hi[8] | ((unsigned)hi[9] << 16);
  u1.y = (unsigned)hi[10] | ((unsigned)hi[11] << 16);
  u1.z = (unsigned)hi[12] | ((unsigned)hi[13] << 16);
  u1.w = (unsigned)hi[14] | ((unsigned)hi[15] << 16);
  *(uint4*)(rowp + ((c0 ^ key)) * 8) = u0;
  *(uint4*)(rowp + (((c0 + 1) ^ key)) * 8) = u1;
  u0.x = (unsigned)lo[0] | ((unsigned)lo[1] << 16);
  u0.y = (unsigned)lo[2] | ((unsigned)lo[3] << 16);
  u0.z = (unsigned)lo[4] | ((unsigned)lo[5] << 16);
  u0.w = (unsigned)lo[6] | ((unsigned)lo[7] << 16);
  u1.x = (unsigned)lo[8] | ((unsigned)lo[9] << 16);
  u1.y = (unsigned)lo[10] | ((unsigned)lo[11] << 16);
  u1.z = (unsigned)lo[12] | ((unsigned)lo[13] << 16);
  u1.w = (unsigned)lo[14] | ((unsigned)lo[15] << 16);
  *(uint4*)(rowp + (((c0 + 4) ^ key)) * 8) = u0;
  *(uint4*)(rowp + (((c0 + 5) ^ key)) * 8) = u1;
}

// ---------------------------------------------------------------------------
// X pre-split: X[m][k] fp32 -> Xp[z][m][packed k] (swizzle key m&7).
// grid (4096, 3), block 256.
// ---------------------------------------------------------------------------
__global__ __launch_bounds__(256)
void convert_x(const float* __restrict__ Q, const float* __restrict__ K,
               const float* __restrict__ V, unsigned short* __restrict__ Xp) {
  const int m = blockIdx.x, z = blockIdx.y;
  const float* src = (z == 0 ? Q : z == 1 ? K : V) + (size_t)m * DM;
  unsigned short* dst =
      Xp + (size_t)z * (8u * 1024 * 1024) + (size_t)m * 2048;
  const int k0 = threadIdx.x * 4;
  float4 f = *(const float4*)(src + k0);
  ushort4 h4, l4;
  splitbf(f.x, h4.x, l4.x);
  splitbf(f.y, h4.y, l4.y);
  splitbf(f.z, h4.z, l4.z);
  splitbf(f.w, h4.w, l4.w);
  int blk = k0 >> 5, ch = (k0 & 31) >> 3, off = k0 & 7, key = m & 7;
  unsigned short* rowp = dst + blk * 64;
  *(ushort4*)(rowp + ((ch ^ key)) * 8 + off) = h4;
  *(ushort4*)(rowp + (((ch + 4) ^ key)) * 8 + off) = l4;
}

// ---------------------------------------------------------------------------
// Wo pre-split: Wo[n][k] fp32 -> Wot[n][packed k] (swizzled like Wt).
// Runs AFTER attn (q_all region dead). grid 1024, block 256.
// ---------------------------------------------------------------------------
__global__ __launch_bounds__(256)
void convert_wo(const float* __restrict__ Wo, unsigned short* __restrict__ Wot) {
  const int n = blockIdx.x;
  const int t = threadIdx.x;
  const int k0 = t * 4;
  float4 f = *(const float4*)(Wo + (size_t)n * DM + k0);
  ushort4 h4, l4;
  splitbf(f.x, h4.x, l4.x);
  splitbf(f.y, h4.y, l4.y);
  splitbf(f.z, h4.z, l4.z);
  splitbf(f.w, h4.w, l4.w);
  int blk = k0 >> 5, ch = (k0 & 31) >> 3, off = k0 & 7, key = n & 7;
  unsigned short* rowp = Wot + (size_t)n * 2048 + blk * 64;
  *(ushort4*)(rowp + ((ch ^ key)) * 8 + off) = h4;
  *(ushort4*)(rowp + (((ch + 4) ^ key)) * 8 + off) = l4;
}

// ---------------------------------------------------------------------------
// 256x256 8-phase counted-vmcnt proj GEMM (unchanged from R1).
// ---------------------------------------------------------------------------
__global__ __launch_bounds__(512, 2)
void proj_gemm(const unsigned short* __restrict__ Xp,
               const unsigned short* __restrict__ Wqt,
               const unsigned short* __restrict__ Wkt,
               const unsigned short* __restrict__ Wvt,
               const float* __restrict__ bq, const float* __restrict__ bk,
               const float* __restrict__ bv, unsigned short* __restrict__ q_all,
               unsigned short* __restrict__ k_all,
               unsigned short* __restrict__ vt) {
  const int ntile = blockIdx.x, mt = blockIdx.y, z = blockIdx.z;
  const unsigned short* Bw = (z == 0 ? Wqt : z == 1 ? Wkt : Wvt);
  const float* bias = (z == 0 ? bq : z == 1 ? bk : bv);

  __shared__ alignas(16) unsigned short As[2][256 * 64];
  __shared__ alignas(16) unsigned short Bs[2][256 * 64];

  const int tid = threadIdx.x;
  const int lane = tid & 63, w = tid >> 6;
  const int l15 = lane & 15, quad = lane >> 4;
  const int wm = (w >> 2) * 128, wn = (w & 3) * 64;
  const int kx = l15 & 7;
  const int r0 = tid >> 3, seg = tid & 7;  // staging: 1024 16B-chunks/half

  const unsigned short* Ap =
      Xp + (size_t)z * (8u * 1024 * 1024) + (size_t)(mt * 256) * 2048;
  const unsigned short* Bp = Bw + (size_t)(ntile * 256) * 2048;

  // A-half hh: rows hh*64 + r0 and 128 + hh*64 + r0   (r0 in [0,64))
#define STAGE_A(bf, hh, t)                                                    \
  do {                                                                        \
    const unsigned short* _s =                                                \
        Ap + (size_t)((hh)*64 + r0) * 2048 + (t)*64 + seg * 8;                \
    unsigned short* _d = &As[bf][((hh)*64 + r0) * 64 + seg * 8];              \
    gld16(_s, _d);                                                            \
    gld16(_s + (size_t)128 * 2048, _d + 128 * 64);                            \
  } while (0)
  // B-half hh: rows ((r0>>5)<<6) + hh*32 + (r0&31), and +128
#define STAGE_B(bf, hh, t)                                                    \
  do {                                                                        \
    int _rb = ((r0 >> 5) << 6) + (hh)*32 + (r0 & 31);                         \
    const unsigned short* _s = Bp + (size_t)_rb * 2048 + (t)*64 + seg * 8;    \
    unsigned short* _d = &Bs[bf][_rb * 64 + seg * 8];                         \
    gld16(_s, _d);                                                            \
    gld16(_s + (size_t)128 * 2048, _d + 128 * 64);                            \
  } while (0)
#define VMW(n) asm volatile("s_waitcnt vmcnt(" #n ")" ::: "memory")

#define PHASE(BUF, QM, QN, STG, VMS)                                          \
  do {                                                                        \
    bf16x8 ah_[4], al_[4], bh_[2], bl_[2];                                    \
    _Pragma("unroll") for (int i_ = 0; i_ < 4; ++i_) {                        \
      const unsigned short* p_ =                                              \
          &As[BUF][(wm + (QM)*64 + i_ * 16 + l15) * 64];                      \
      ah_[i_] = *(const bf16x8*)(p_ + ((quad ^ kx)) * 8);                     \
      al_[i_] = *(const bf16x8*)(p_ + (((quad + 4) ^ kx)) * 8);               \
    }                                                                         \
    _Pragma("unroll") for (int j_ = 0; j_ < 2; ++j_) {                        \
      const unsigned short* p_ =                                              \
          &Bs[BUF][(wn + (QN)*32 + j_ * 16 + l15) * 64];                      \
      bh_[j_] = *(const bf16x8*)(p_ + ((quad ^ kx)) * 8);                     \
      bl_[j_] = *(const bf16x8*)(p_ + (((quad + 4) ^ kx)) * 8);               \
    }                                                                         \
    STG;                                                                      \
    VMS;                                                                      \
    asm volatile("s_waitcnt lgkmcnt(8)" ::: "memory");                        \
    __builtin_amdgcn_s_barrier();                                             \
    asm volatile("s_waitcnt lgkmcnt(0)" ::: "memory");                        \
    __builtin_amdgcn_sched_barrier(0);                                        \
    __builtin_amdgcn_s_setprio(1);                                            \
    _Pragma("unroll") for (int j_ = 0; j_ < 2; ++j_)                          \
        _Pragma("unroll") for (int i_ = 0; i_ < 4; ++i_) {                    \
      acc[QM][QN][i_][j_] = __builtin_amdgcn_mfma_f32_16x16x32_bf16(          \
          ah_[i_], bh_[j_], acc[QM][QN][i_][j_], 0, 0, 0);                    \
      acc[QM][QN][i_][j_] = __builtin_amdgcn_mfma_f32_16x16x32_bf16(          \
          al_[i_], bh_[j_], acc[QM][QN][i_][j_], 0, 0, 0);                    \
      acc[QM][QN][i_][j_] = __builtin_amdgcn_mfma_f32_16x16x32_bf16(          \
          ah_[i_], bl_[j_], acc[QM][QN][i_][j_], 0, 0, 0);                    \
    }                                                                         \
    __builtin_amdgcn_s_setprio(0);                                            \
    __builtin_amdgcn_sched_barrier(0);                                        \
    __builtin_amdgcn_s_barrier();                                             \
  } while (0)

  f32x4 acc[2][2][4][2];
#pragma unroll
  for (int a0 = 0; a0 < 2; ++a0)
#pragma unroll
    for (int a1 = 0; a1 < 2; ++a1)
#pragma unroll
      for (int a2 = 0; a2 < 4; ++a2)
#pragma unroll
        for (int a3 = 0; a3 < 2; ++a3)
          acc[a0][a1][a2][a3] = (f32x4){0.f, 0.f, 0.f, 0.f};

  // prologue: tile0 fully, then tile1 {B0, A0}; vmcnt(4) lands tile0.
  STAGE_B(0, 0, 0);
  STAGE_A(0, 0, 0);
  STAGE_A(0, 1, 0);
  STAGE_B(0, 1, 0);
  STAGE_B(1, 0, 1);
  STAGE_A(1, 0, 1);
  VMW(4);
  __builtin_amdgcn_s_barrier();

#pragma unroll 1
  for (int it2 = 0; it2 < 16; ++it2) {
    const int O = 2 * it2 + 1;        // odd K-step, buf1, phases 5-8
    const int En = 2 * it2 + 2;       // next even K-step -> buf0
    const int On = 2 * it2 + 3;       // next odd K-step -> buf1
    const bool sE = (it2 < 15);
    PHASE(0, 0, 0, STAGE_A(1, 1, O), (void)0);
    PHASE(0, 1, 0, STAGE_B(1, 1, O), (void)0);
    PHASE(0, 0, 1, if (sE) STAGE_B(0, 0, En), (void)0);
    PHASE(0, 1, 1, if (sE) STAGE_A(0, 0, En),
          if (sE) { VMW(4); } else { VMW(0); });
    PHASE(1, 0, 0, if (sE) STAGE_A(0, 1, En), (void)0);
    PHASE(1, 1, 0, if (sE) STAGE_B(0, 1, En), (void)0);
    PHASE(1, 0, 1, if (sE) STAGE_B(1, 0, On), (void)0);
    PHASE(1, 1, 1, if (sE) STAGE_A(1, 0, On), if (sE) VMW(4));
  }
#undef PHASE
#undef VMW
#undef STAGE_A
#undef STAGE_B

  if (z <= 1) {
    unsigned short* dst = (z == 0 ? q_all : k_all);
#pragma unroll
    for (int qm = 0; qm < 2; ++qm)
#pragma unroll
      for (int qn = 0; qn < 2; ++qn)
#pragma unroll
        for (int i = 0; i < 4; ++i)
#pragma unroll
          for (int j = 0; j < 2; ++j) {
            int n = ntile * 256 + wn + qn * 32 + j * 16 + l15;
            int hh_ = n >> 6, d = n & 63;
            int chi = (d >> 5) * 8 + ((d & 31) >> 3);
            float bn = bias[n];
#pragma unroll
            for (int r = 0; r < 4; ++r) {
              int m = mt * 256 + wm + qm * 64 + i * 16 + quad * 4 + r;
              int key = m & 15;
              size_t rb = (size_t)m * 2048 + hh_ * 128;
              unsigned short hv, lv;
              splitbf(acc[qm][qn][i][j][r] + bn, hv, lv);
              dst[rb + ((chi ^ key)) * 8 + (d & 7)] = hv;
              dst[rb + (((chi + 4) ^ key)) * 8 + (d & 7)] = lv;
            }
          }
  } else {
#pragma unroll
    for (int qm = 0; qm < 2; ++qm)
#pragma unroll
      for (int qn = 0; qn < 2; ++qn)
#pragma unroll
        for (int i = 0; i < 4; ++i)
#pragma unroll
          for (int j = 0; j < 2; ++j) {
            int n = ntile * 256 + wn + qn * 32 + j * 16 + l15;
            int h = n >> 6, d = n & 63;
            float bn = bias[n];
            int m0 = mt * 256 + wm + qm * 64 + i * 16 + quad * 4;
            int b = m0 >> 11, s0_ = m0 & 2047;
            int kt = s0_ >> 6, sl = s0_ & 63;
            int ch = sl >> 3, off = sl & 7, key = d & 15;
            ushort4 h4, l4;
            splitbf(acc[qm][qn][i][j][0] + bn, h4.x, l4.x);
            splitbf(acc[qm][qn][i][j][1] + bn, h4.y, l4.y);
            splitbf(acc[qm][qn][i][j][2] + bn, h4.z, l4.z);
            splitbf(acc[qm][qn][i][j][3] + bn, h4.w, l4.w);
            size_t base =
                (size_t)(b * NH + h) * 262144 + (size_t)d * 4096 + kt * 128;
            *(ushort4*)(vt + base + ((ch ^ key)) * 8 + off) = h4;
            *(ushort4*)(vt + base + (((ch + 8) ^ key)) * 8 + off) = l4;
          }
  }
}

// ---------------------------------------------------------------------------
// Single-barrier dbuf output GEMM (unchanged).
// ---------------------------------------------------------------------------
__global__ __launch_bounds__(256)
void out_gemm(const unsigned short* __restrict__ a_all,
              const unsigned short* __restrict__ Wot,
              const float* __restrict__ bo, float* __restrict__ out) {
  const int ntile = blockIdx.x, mt = blockIdx.y;

  __shared__ alignas(16) unsigned short As[2][64 * 64];
  __shared__ alignas(16) unsigned short Bs[2][128 * 64];

  const int tid = threadIdx.x;
  const int lane = tid & 63, w = tid >> 6;
  const int l15 = lane & 15, quad = lane >> 4;
  const int wn = w * 32;
  const int kx = l15 & 7;

  const unsigned short* Ap = a_all + (size_t)(mt * 64) * 2048;
  const unsigned short* Bp = Wot + (size_t)(ntile * 128) * 2048;

#pragma unroll
  for (int it = 0; it < 2; ++it) {
    int s = tid + it * 256;
    int r = s >> 3, seg = s & 7;
    gld16(Ap + (size_t)r * 2048 + seg * 8, &As[0][s * 8]);
  }
#pragma unroll
  for (int it = 0; it < 4; ++it) {
    int s = tid + it * 256;
    int r = s >> 3, seg = s & 7;
    gld16(Bp + (size_t)r * 2048 + seg * 8, &Bs[0][s * 8]);
  }

  f32x4 acc[4][2];
#pragma unroll
  for (int i = 0; i < 4; ++i)
#pragma unroll
    for (int j = 0; j < 2; ++j) acc[i][j] = (f32x4){0.f, 0.f, 0.f, 0.f};

  int cur = 0;
  for (int kk = 0; kk < 32; ++kk) {
    __syncthreads();

    if (kk + 1 < 32) {
      int blk = (kk + 1) * 64;
#pragma unroll
      for (int it = 0; it < 2; ++it) {
        int s = tid + it * 256;
        int r = s >> 3, seg = s & 7;
        gld16(Ap + (size_t)r * 2048 + blk + seg * 8, &As[cur ^ 1][s * 8]);
      }
#pragma unroll
      for (int it = 0; it < 4; ++it) {
        int s = tid + it * 256;
        int r = s >> 3, seg = s & 7;
        gld16(Bp + (size_t)r * 2048 + blk + seg * 8, &Bs[cur ^ 1][s * 8]);
      }
    }

    bf16x8 ah[4], al[4];
#pragma unroll
    for (int i = 0; i < 4; ++i) {
      const unsigned short* p = &As[cur][(i * 16 + l15) * 64];
      ah[i] = *(const bf16x8*)(p + ((quad ^ kx)) * 8);
      al[i] = *(const bf16x8*)(p + (((quad + 4) ^ kx)) * 8);
    }
#pragma unroll
    for (int j = 0; j < 2; ++j) {
      const unsigned short* p = &Bs[cur][(wn + j * 16 + l15) * 64];
      bf16x8 bh = *(const bf16x8*)(p + ((quad ^ kx)) * 8);
      bf16x8 bl = *(const bf16x8*)(p + (((quad + 4) ^ kx)) * 8);
#pragma unroll
      for (int i = 0; i < 4; ++i) {
        acc[i][j] = __builtin_amdgcn_mfma_f32_16x16x32_bf16(ah[i], bh, acc[i][j], 0, 0, 0);
        acc[i][j] = __builtin_amdgcn_mfma_f32_16x16x32_bf16(al[i], bh, acc[i][j], 0, 0, 0);
        acc[i][j] = __builtin_amdgcn_mfma_f32_16x16x32_bf16(ah[i], bl, acc[i][j], 0, 0, 0);
      }
    }
    cur ^= 1;
  }

#pragma unroll
  for (int i = 0; i < 4; ++i)
#pragma unroll
    for (int j = 0; j < 2; ++j) {
      int n = ntile * 128 + wn + j * 16 + l15;
      float bn = bo[n];
#pragma unroll
      for (int r = 0; r < 4; ++r) {
        int m = mt * 64 + i * 16 + quad * 4 + r;
        out[(size_t)m * DM + n] = acc[i][j][r] + bn;
      }
    }
}

// ---------------------------------------------------------------------------
// MFMA flash attention, occupancy-doubled: QBLK=64 (16 q-rows/wave), KVBLK=32,
// LDS 36 KB (Ks 2x8K dbuf, Vs 2x8K dbuf, Ps 4K) -> 4 blocks/CU, grid
// (32,16,2)=1024 blocks all co-resident = 16 waves/CU (was 2 blocks/CU, 8).
// V half-tile staged via pre-swizzled global source + linear LDS dest +
// fresh 8-slot read swizzle (slot p holds logical chunk p^(d&7)). Ps uses a
// 4-chunk swizzle, key (row>>1)&3 on both write and read. Wave-private Ps
// (no P barriers), 1 staging barrier/tile, setprio around MFMA clusters.
// Math identical to prior rounds (hi/lo splits, exp(s/8), l-reduce).
// ---------------------------------------------------------------------------
__global__ __launch_bounds__(256, 4)
void attn_kernel(const unsigned short* __restrict__ q_all,
                 const unsigned short* __restrict__ k_all,
                 const unsigned short* __restrict__ vt,
                 unsigned short* __restrict__ a_all) {
  const int qt = blockIdx.x, h = blockIdx.y, b = blockIdx.z;
  const unsigned short* vp = vt + (size_t)(b * NH + h) * 262144;

  __shared__ alignas(16) unsigned short Ks[2][32 * 128];  // 16 KB
  __shared__ alignas(16) unsigned short Vs[2][64 * 64];   // 16 KB
  __shared__ alignas(16) unsigned short Ps[64 * 32];      // 4 KB

  const int tid = threadIdx.x;
  const int lane = tid & 63;
  const int w = tid >> 6;
  const int l15 = lane & 15;
  const int quad = lane >> 4;

  // Q rows for this wave: qt*64 + w*16 + [0,16)
  bf16x8 qf[2][2];
  {
    const unsigned short* qrow =
        q_all + (size_t)(b * SLEN + qt * 64 + w * 16 + l15) * 2048 + h * 128;
#pragma unroll
    for (int kb = 0; kb < 2; ++kb) {
      qf[kb][0] = *(const bf16x8*)(qrow + ((kb * 8 + quad) ^ l15) * 8);
      qf[kb][1] = *(const bf16x8*)(qrow + ((kb * 8 + quad + 4) ^ l15) * 8);
    }
  }

#define STAGE_KV(kt_, buf_)                                                   \
  do {                                                                        \
    const unsigned short* ksrc =                                              \
        k_all + (size_t)(b * SLEN + (kt_)*32) * 2048 + h * 128;               \
    _Pragma("unroll") for (int it = 0; it < 2; ++it) {                        \
      int ss = it * 256 + tid;                                                \
      int r = ss >> 4, p = ss & 15;                                           \
      gld16(ksrc + (size_t)r * 2048 + p * 8, &Ks[buf_][ss * 8]);              \
    }                                                                         \
    int t64 = (kt_) >> 1, h32 = (kt_)&1;                                      \
    _Pragma("unroll") for (int it = 0; it < 2; ++it) {                        \
      int ss = it * 256 + tid;                                                \
      int d = ss >> 3, p = ss & 7;                                            \
      int l = p ^ (d & 7);                                                    \
      int c = (l < 4 ? h32 * 4 + l : 4 + h32 * 4 + l);                        \
      gld16(vp + (size_t)d * 4096 + t64 * 128 + ((c ^ (d & 15))) * 8,         \
            &Vs[buf_][ss * 8]);                                               \
    }                                                                         \
  } while (0)

  // prologue: stage kt=0
  STAGE_KV(0, 0);

  f32x4 o[4];
  float lpart[4];
#pragma unroll
  for (int nt = 0; nt < 4; ++nt) o[nt] = (f32x4){0.f, 0.f, 0.f, 0.f};
#pragma unroll
  for (int r = 0; r < 4; ++r) lpart[r] = 0.f;

  int cur = 0;
#pragma unroll 1
  for (int kt = 0; kt < 64; ++kt) {
    __syncthreads();  // glds(kt) done (aged through prev iteration for kt>0)

    if (kt + 1 < 64) STAGE_KV(kt + 1, cur ^ 1);

    f32x4 sc[2];
#pragma unroll
    for (int ct = 0; ct < 2; ++ct) sc[ct] = (f32x4){0.f, 0.f, 0.f, 0.f};
    __builtin_amdgcn_s_setprio(1);
#pragma unroll
    for (int ct = 0; ct < 2; ++ct) {
      const unsigned short* kbase = &Ks[cur][(ct * 16 + l15) * 128];
#pragma unroll
      for (int kb = 0; kb < 2; ++kb) {
        bf16x8 kh = *(const bf16x8*)(kbase + ((kb * 8 + quad) ^ l15) * 8);
        bf16x8 kl = *(const bf16x8*)(kbase + ((kb * 8 + quad + 4) ^ l15) * 8);
        sc[ct] = __builtin_amdgcn_mfma_f32_16x16x32_bf16(qf[kb][0], kh, sc[ct], 0, 0, 0);
        sc[ct] = __builtin_amdgcn_mfma_f32_16x16x32_bf16(qf[kb][0], kl, sc[ct], 0, 0, 0);
        sc[ct] = __builtin_amdgcn_mfma_f32_16x16x32_bf16(qf[kb][1], kh, sc[ct], 0, 0, 0);
      }
    }
    __builtin_amdgcn_s_setprio(0);

#pragma unroll
    for (int ct = 0; ct < 2; ++ct)
#pragma unroll
      for (int r = 0; r < 4; ++r) {
        float e = __expf(sc[ct][r] * 0.125f);
        lpart[r] += e;
        int prow = w * 16 + quad * 4 + r;
        int pk = (prow >> 1) & 3;
        Ps[prow * 32 + (((ct * 2 + (l15 >> 3)) ^ pk)) * 8 + (l15 & 7)] =
            f2bf(e);
      }
    // P is wave-private: same-wave DS order + lgkmcnt fence suffices.
    asm volatile("s_waitcnt lgkmcnt(0)" ::: "memory");
    __builtin_amdgcn_sched_barrier(0);

    {
      int rk = (l15 >> 1) & 3;
      bf16x8 pf =
          *(const bf16x8*)(&Ps[(w * 16 + l15) * 32 + ((quad ^ rk)) * 8]);
      __builtin_amdgcn_s_setprio(1);
#pragma unroll
      for (int nt = 0; nt < 4; ++nt) {
        const unsigned short* vb = &Vs[cur][(nt * 16 + l15) * 64];
        bf16x8 vh = *(const bf16x8*)(vb + ((quad ^ (l15 & 7))) * 8);
        bf16x8 vl = *(const bf16x8*)(vb + (((quad + 4) ^ (l15 & 7))) * 8);
        o[nt] = __builtin_amdgcn_mfma_f32_16x16x32_bf16(pf, vh, o[nt], 0, 0, 0);
        o[nt] = __builtin_amdgcn_mfma_f32_16x16x32_bf16(pf, vl, o[nt], 0, 0, 0);
      }
      __builtin_amdgcn_s_setprio(0);
    }
    cur ^= 1;
  }
#undef STAGE_KV

  float inv[4];
#pragma unroll
  for (int r = 0; r < 4; ++r) {
    float lv = lpart[r];
#pragma unroll
    for (int m = 1; m < 16; m <<= 1) lv += __shfl_xor(lv, m, 64);
    inv[r] = 1.f / lv;
  }
#pragma unroll
  for (int nt = 0; nt < 4; ++nt) {
    int c = h * 64 + nt * 16 + l15;
    int Bb = c >> 5;
    int d32 = c & 31;
    int ch = d32 >> 3, off = d32 & 7;
#pragma unroll
    for (int r = 0; r < 4; ++r) {
      float val = o[nt][r] * inv[r];
      int srow = qt * 64 + w * 16 + quad * 4 + r;
      int key = srow & 7;
      size_t g = (size_t)(b * SLEN + srow) * 2048 + Bb * 64;
      unsigned short hv, lv2;
      splitbf(val, hv, lv2);
      a_all[g + ((ch ^ key)) * 8 + off] = hv;
      a_all[g + (((ch + 4) ^ key)) * 8 + off] = lv2;
    }
  }
}

extern "C" void kernel_launch(void* const* d_in, const int* in_sizes, int n_in,
                              void* d_out, int out_size, void* d_ws,
                              size_t ws_size, hipStream_t stream) {
  (void)in_sizes; (void)n_in; (void)out_size; (void)ws_size;
  const float* Q = (const float*)d_in[0];
  const float* K = (const float*)d_in[1];
  const float* V = (const float*)d_in[2];
  const float* Wq = (const float*)d_in[3];
  const float* bq = (const float*)d_in[4];
  const float* Wk = (const float*)d_in[5];
  const float* bk = (const float*)d_in[6];
  const float* Wv = (const float*)d_in[7];
  const float* bv = (const float*)d_in[8];
  const float* Wo = (const float*)d_in[9];
  const float* bo = (const float*)d_in[10];
  float* out = (float*)d_out;

  // ws layout (u16 units), 112 MB total:
  //   q_all [0,8M)  k_all [8M,16M)  vt [16M,24M)
  //   a_all [24M,32M) -- Wqt/Wkt/Wvt overlaid (dead before attn writes a_all)
  //   Xp    [32M,56M) -- 3x 8M u16 packed split inputs (dead after proj)
  //   Wot overlays q_all (dead after attn)
  unsigned short* us = (unsigned short*)d_ws;
  const size_t M8 = 8u * 1024 * 1024;
  unsigned short* q_all = us;
  unsigned short* k_all = us + M8;
  unsigned short* vt = us + 2 * M8;
  unsigned short* a_all = us + 3 * M8;
  unsigned short* Wqt = a_all;
  unsigned short* Wkt = a_all + 2 * 1024 * 1024;
  unsigned short* Wvt = a_all + 4 * 1024 * 1024;
  unsigned short* Xp = us + 4 * M8;
  unsigned short* Wot = q_all;

  convert_w<<<dim3(16, 16, 3), 256, 0, stream>>>(Wq, Wk, Wv, Wqt, Wkt, Wvt);
  convert_x<<<dim3(4096, 3), 256, 0, stream>>>(Q, K, V, Xp);
  proj_gemm<<<dim3(4, 16, 3), 512, 0, stream>>>(Xp, Wqt, Wkt, Wvt, bq, bk, bv,
                                                q_all, k_all, vt);
  attn_kernel<<<dim3(SLEN / 64, NH, BATCH), 256, 0, stream>>>(q_all, k_all,
                                                              vt, a_all);
  convert_wo<<<dim3(1024), 256, 0, stream>>>(Wo, Wot);
  out_gemm<<<dim3(8, 64), 256, 0, stream>>>(a_all, Wot, bo, out);
}

// Round 5
// 339.537 us; speedup vs baseline: 1.0817x; 1.0817x over previous
//
#include <hip/hip_runtime.h>
#include <math.h>

#define BATCH 2
#define SLEN 2048
#define DM 1024
#define NH 16
#define DK 64
#define STILES (SLEN / 64)  // 32

typedef __attribute__((ext_vector_type(8))) __bf16 bf16x8;
typedef __attribute__((ext_vector_type(4))) float f32x4;

__device__ __forceinline__ unsigned short f2bf(float x) {  // round-nearest
  unsigned u = __builtin_bit_cast(unsigned, x);
  unsigned r = (u + 0x7fffu + ((u >> 16) & 1u)) >> 16;
  return (unsigned short)r;
}
// cheap truncation split: x ~= hi + lo to ~2^-16 relative
__device__ __forceinline__ void splitbf(float x, unsigned short& h,
                                        unsigned short& l) {
  unsigned u = __builtin_bit_cast(unsigned, x);
  h = (unsigned short)(u >> 16);
  float hf = __builtin_bit_cast(float, u & 0xffff0000u);
  l = (unsigned short)(__builtin_bit_cast(unsigned, x - hf) >> 16);
}

// async global->LDS, 16 B per lane
__device__ __forceinline__ void gld16(const unsigned short* g,
                                      unsigned short* l) {
  __builtin_amdgcn_global_load_lds(
      (const __attribute__((address_space(1))) void*)g,
      (__attribute__((address_space(3))) void*)l, 16, 0, 0);
}

// ---------------------------------------------------------------------------
// Weight transpose+split -> Wt[n][packed k], 64-u16 k-blocks [hi32|lo32],
// 16-B chunks XOR-swizzled with key (n&7).
// ---------------------------------------------------------------------------
__global__ __launch_bounds__(256)
void convert_w(const float* __restrict__ Wq, const float* __restrict__ Wk,
               const float* __restrict__ Wv, unsigned short* __restrict__ Wqt,
               unsigned short* __restrict__ Wkt,
               unsigned short* __restrict__ Wvt) {
  const int kb = blockIdx.x, h = blockIdx.y, z = blockIdx.z;
  const float* W = (z == 0 ? Wq : z == 1 ? Wk : Wv) +
                   ((size_t)h * DM + kb * 64) * DK;
  unsigned short* D = (z == 0 ? Wqt : z == 1 ? Wkt : Wvt);

  __shared__ float T[64][65];
  const int tid = threadIdx.x;
  {
    int r = tid >> 2, c0 = (tid & 3) * 16;
#pragma unroll
    for (int i = 0; i < 4; ++i) {
      float4 f = *(const float4*)(W + (size_t)r * DK + c0 + i * 4);
      T[r][c0 + i * 4 + 0] = f.x;
      T[r][c0 + i * 4 + 1] = f.y;
      T[r][c0 + i * 4 + 2] = f.z;
      T[r][c0 + i * 4 + 3] = f.w;
    }
  }
  __syncthreads();
  int j = tid >> 2, p = tid & 3;
  int n = h * 64 + j;
  int kloc = p * 16;
  unsigned short hi[16], lo[16];
#pragma unroll
  for (int i = 0; i < 16; ++i) splitbf(T[kloc + i][j], hi[i], lo[i]);
  int kglob = kb * 64 + kloc;
  int blk = kglob >> 5;
  int c0 = (kglob & 31) >> 3;
  int key = n & 7;
  unsigned short* rowp = D + (size_t)n * 2048 + blk * 64;
  uint4 u0, u1;
  u0.x = (unsigned)hi[0] | ((unsigned)hi[1] << 16);
  u0.y = (unsigned)hi[2] | ((unsigned)hi[3] << 16);
  u0.z = (unsigned)hi[4] | ((unsigned)hi[5] << 16);
  u0.w = (unsigned)hi[6] | ((unsigned)hi[7] << 16);
  u1.x = (unsigned)hi[8] | ((unsigned)hi[9] << 16);
  u1.y = (unsigned)hi[10] | ((unsigned)hi[11] << 16);
  u1.z = (unsigned)hi[12] | ((unsigned)hi[13] << 16);
  u1.w = (unsigned)hi[14] | ((unsigned)hi[15] << 16);
  *(uint4*)(rowp + ((c0 ^ key)) * 8) = u0;
  *(uint4*)(rowp + (((c0 + 1) ^ key)) * 8) = u1;
  u0.x = (unsigned)lo[0] | ((unsigned)lo[1] << 16);
  u0.y = (unsigned)lo[2] | ((unsigned)lo[3] << 16);
  u0.z = (unsigned)lo[4] | ((unsigned)lo[5] << 16);
  u0.w = (unsigned)lo[6] | ((unsigned)lo[7] << 16);
  u1.x = (unsigned)lo[8] | ((unsigned)lo[9] << 16);
  u1.y = (unsigned)lo[10] | ((unsigned)lo[11] << 16);
  u1.z = (unsigned)lo[12] | ((unsigned)lo[13] << 16);
  u1.w = (unsigned)lo[14] | ((unsigned)lo[15] << 16);
  *(uint4*)(rowp + (((c0 + 4) ^ key)) * 8) = u0;
  *(uint4*)(rowp + (((c0 + 5) ^ key)) * 8) = u1;
}

// ---------------------------------------------------------------------------
// X pre-split: X[m][k] fp32 -> Xp[z][m][packed k] (swizzle key m&7).
// grid (4096, 3), block 256.
// ---------------------------------------------------------------------------
__global__ __launch_bounds__(256)
void convert_x(const float* __restrict__ Q, const float* __restrict__ K,
               const float* __restrict__ V, unsigned short* __restrict__ Xp) {
  const int m = blockIdx.x, z = blockIdx.y;
  const float* src = (z == 0 ? Q : z == 1 ? K : V) + (size_t)m * DM;
  unsigned short* dst =
      Xp + (size_t)z * (8u * 1024 * 1024) + (size_t)m * 2048;
  const int k0 = threadIdx.x * 4;
  float4 f = *(const float4*)(src + k0);
  ushort4 h4, l4;
  splitbf(f.x, h4.x, l4.x);
  splitbf(f.y, h4.y, l4.y);
  splitbf(f.z, h4.z, l4.z);
  splitbf(f.w, h4.w, l4.w);
  int blk = k0 >> 5, ch = (k0 & 31) >> 3, off = k0 & 7, key = m & 7;
  unsigned short* rowp = dst + blk * 64;
  *(ushort4*)(rowp + ((ch ^ key)) * 8 + off) = h4;
  *(ushort4*)(rowp + (((ch + 4) ^ key)) * 8 + off) = l4;
}

// ---------------------------------------------------------------------------
// Wo pre-split: Wo[n][k] fp32 -> Wot[n][packed k] (swizzled like Wt).
// Runs AFTER attn (q_all region dead). grid 1024, block 256.
// ---------------------------------------------------------------------------
__global__ __launch_bounds__(256)
void convert_wo(const float* __restrict__ Wo, unsigned short* __restrict__ Wot) {
  const int n = blockIdx.x;
  const int t = threadIdx.x;
  const int k0 = t * 4;
  float4 f = *(const float4*)(Wo + (size_t)n * DM + k0);
  ushort4 h4, l4;
  splitbf(f.x, h4.x, l4.x);
  splitbf(f.y, h4.y, l4.y);
  splitbf(f.z, h4.z, l4.z);
  splitbf(f.w, h4.w, l4.w);
  int blk = k0 >> 5, ch = (k0 & 31) >> 3, off = k0 & 7, key = n & 7;
  unsigned short* rowp = Wot + (size_t)n * 2048 + blk * 64;
  *(ushort4*)(rowp + ((ch ^ key)) * 8 + off) = h4;
  *(ushort4*)(rowp + (((ch + 4) ^ key)) * 8 + off) = l4;
}

// ---------------------------------------------------------------------------
// 256x256 8-phase counted-vmcnt proj GEMM (unchanged from R1).
// ---------------------------------------------------------------------------
__global__ __launch_bounds__(512, 2)
void proj_gemm(const unsigned short* __restrict__ Xp,
               const unsigned short* __restrict__ Wqt,
               const unsigned short* __restrict__ Wkt,
               const unsigned short* __restrict__ Wvt,
               const float* __restrict__ bq, const float* __restrict__ bk,
               const float* __restrict__ bv, unsigned short* __restrict__ q_all,
               unsigned short* __restrict__ k_all,
               unsigned short* __restrict__ vt) {
  const int ntile = blockIdx.x, mt = blockIdx.y, z = blockIdx.z;
  const unsigned short* Bw = (z == 0 ? Wqt : z == 1 ? Wkt : Wvt);
  const float* bias = (z == 0 ? bq : z == 1 ? bk : bv);

  __shared__ alignas(16) unsigned short As[2][256 * 64];
  __shared__ alignas(16) unsigned short Bs[2][256 * 64];

  const int tid = threadIdx.x;
  const int lane = tid & 63, w = tid >> 6;
  const int l15 = lane & 15, quad = lane >> 4;
  const int wm = (w >> 2) * 128, wn = (w & 3) * 64;
  const int kx = l15 & 7;
  const int r0 = tid >> 3, seg = tid & 7;  // staging: 1024 16B-chunks/half

  const unsigned short* Ap =
      Xp + (size_t)z * (8u * 1024 * 1024) + (size_t)(mt * 256) * 2048;
  const unsigned short* Bp = Bw + (size_t)(ntile * 256) * 2048;

  // A-half hh: rows hh*64 + r0 and 128 + hh*64 + r0   (r0 in [0,64))
#define STAGE_A(bf, hh, t)                                                    \
  do {                                                                        \
    const unsigned short* _s =                                                \
        Ap + (size_t)((hh)*64 + r0) * 2048 + (t)*64 + seg * 8;                \
    unsigned short* _d = &As[bf][((hh)*64 + r0) * 64 + seg * 8];              \
    gld16(_s, _d);                                                            \
    gld16(_s + (size_t)128 * 2048, _d + 128 * 64);                            \
  } while (0)
  // B-half hh: rows ((r0>>5)<<6) + hh*32 + (r0&31), and +128
#define STAGE_B(bf, hh, t)                                                    \
  do {                                                                        \
    int _rb = ((r0 >> 5) << 6) + (hh)*32 + (r0 & 31);                         \
    const unsigned short* _s = Bp + (size_t)_rb * 2048 + (t)*64 + seg * 8;    \
    unsigned short* _d = &Bs[bf][_rb * 64 + seg * 8];                         \
    gld16(_s, _d);                                                            \
    gld16(_s + (size_t)128 * 2048, _d + 128 * 64);                            \
  } while (0)
#define VMW(n) asm volatile("s_waitcnt vmcnt(" #n ")" ::: "memory")

#define PHASE(BUF, QM, QN, STG, VMS)                                          \
  do {                                                                        \
    bf16x8 ah_[4], al_[4], bh_[2], bl_[2];                                    \
    _Pragma("unroll") for (int i_ = 0; i_ < 4; ++i_) {                        \
      const unsigned short* p_ =                                              \
          &As[BUF][(wm + (QM)*64 + i_ * 16 + l15) * 64];                      \
      ah_[i_] = *(const bf16x8*)(p_ + ((quad ^ kx)) * 8);                     \
      al_[i_] = *(const bf16x8*)(p_ + (((quad + 4) ^ kx)) * 8);               \
    }                                                                         \
    _Pragma("unroll") for (int j_ = 0; j_ < 2; ++j_) {                        \
      const unsigned short* p_ =                                              \
          &Bs[BUF][(wn + (QN)*32 + j_ * 16 + l15) * 64];                      \
      bh_[j_] = *(const bf16x8*)(p_ + ((quad ^ kx)) * 8);                     \
      bl_[j_] = *(const bf16x8*)(p_ + (((quad + 4) ^ kx)) * 8);               \
    }                                                                         \
    STG;                                                                      \
    VMS;                                                                      \
    asm volatile("s_waitcnt lgkmcnt(8)" ::: "memory");                        \
    __builtin_amdgcn_s_barrier();                                             \
    asm volatile("s_waitcnt lgkmcnt(0)" ::: "memory");                        \
    __builtin_amdgcn_sched_barrier(0);                                        \
    __builtin_amdgcn_s_setprio(1);                                            \
    _Pragma("unroll") for (int j_ = 0; j_ < 2; ++j_)                          \
        _Pragma("unroll") for (int i_ = 0; i_ < 4; ++i_) {                    \
      acc[QM][QN][i_][j_] = __builtin_amdgcn_mfma_f32_16x16x32_bf16(          \
          ah_[i_], bh_[j_], acc[QM][QN][i_][j_], 0, 0, 0);                    \
      acc[QM][QN][i_][j_] = __builtin_amdgcn_mfma_f32_16x16x32_bf16(          \
          al_[i_], bh_[j_], acc[QM][QN][i_][j_], 0, 0, 0);                    \
      acc[QM][QN][i_][j_] = __builtin_amdgcn_mfma_f32_16x16x32_bf16(          \
          ah_[i_], bl_[j_], acc[QM][QN][i_][j_], 0, 0, 0);                    \
    }                                                                         \
    __builtin_amdgcn_s_setprio(0);                                            \
    __builtin_amdgcn_sched_barrier(0);                                        \
    __builtin_amdgcn_s_barrier();                                             \
  } while (0)

  f32x4 acc[2][2][4][2];
#pragma unroll
  for (int a0 = 0; a0 < 2; ++a0)
#pragma unroll
    for (int a1 = 0; a1 < 2; ++a1)
#pragma unroll
      for (int a2 = 0; a2 < 4; ++a2)
#pragma unroll
        for (int a3 = 0; a3 < 2; ++a3)
          acc[a0][a1][a2][a3] = (f32x4){0.f, 0.f, 0.f, 0.f};

  // prologue: tile0 fully, then tile1 {B0, A0}; vmcnt(4) lands tile0.
  STAGE_B(0, 0, 0);
  STAGE_A(0, 0, 0);
  STAGE_A(0, 1, 0);
  STAGE_B(0, 1, 0);
  STAGE_B(1, 0, 1);
  STAGE_A(1, 0, 1);
  VMW(4);
  __builtin_amdgcn_s_barrier();

#pragma unroll 1
  for (int it2 = 0; it2 < 16; ++it2) {
    const int O = 2 * it2 + 1;        // odd K-step, buf1, phases 5-8
    const int En = 2 * it2 + 2;       // next even K-step -> buf0
    const int On = 2 * it2 + 3;       // next odd K-step -> buf1
    const bool sE = (it2 < 15);
    PHASE(0, 0, 0, STAGE_A(1, 1, O), (void)0);
    PHASE(0, 1, 0, STAGE_B(1, 1, O), (void)0);
    PHASE(0, 0, 1, if (sE) STAGE_B(0, 0, En), (void)0);
    PHASE(0, 1, 1, if (sE) STAGE_A(0, 0, En),
          if (sE) { VMW(4); } else { VMW(0); });
    PHASE(1, 0, 0, if (sE) STAGE_A(0, 1, En), (void)0);
    PHASE(1, 1, 0, if (sE) STAGE_B(0, 1, En), (void)0);
    PHASE(1, 0, 1, if (sE) STAGE_B(1, 0, On), (void)0);
    PHASE(1, 1, 1, if (sE) STAGE_A(1, 0, On), if (sE) VMW(4));
  }
#undef PHASE
#undef VMW
#undef STAGE_A
#undef STAGE_B

  if (z <= 1) {
    unsigned short* dst = (z == 0 ? q_all : k_all);
#pragma unroll
    for (int qm = 0; qm < 2; ++qm)
#pragma unroll
      for (int qn = 0; qn < 2; ++qn)
#pragma unroll
        for (int i = 0; i < 4; ++i)
#pragma unroll
          for (int j = 0; j < 2; ++j) {
            int n = ntile * 256 + wn + qn * 32 + j * 16 + l15;
            int hh_ = n >> 6, d = n & 63;
            int chi = (d >> 5) * 8 + ((d & 31) >> 3);
            float bn = bias[n];
#pragma unroll
            for (int r = 0; r < 4; ++r) {
              int m = mt * 256 + wm + qm * 64 + i * 16 + quad * 4 + r;
              int key = m & 15;
              size_t rb = (size_t)m * 2048 + hh_ * 128;
              unsigned short hv, lv;
              splitbf(acc[qm][qn][i][j][r] + bn, hv, lv);
              dst[rb + ((chi ^ key)) * 8 + (d & 7)] = hv;
              dst[rb + (((chi + 4) ^ key)) * 8 + (d & 7)] = lv;
            }
          }
  } else {
#pragma unroll
    for (int qm = 0; qm < 2; ++qm)
#pragma unroll
      for (int qn = 0; qn < 2; ++qn)
#pragma unroll
        for (int i = 0; i < 4; ++i)
#pragma unroll
          for (int j = 0; j < 2; ++j) {
            int n = ntile * 256 + wn + qn * 32 + j * 16 + l15;
            int h = n >> 6, d = n & 63;
            float bn = bias[n];
            int m0 = mt * 256 + wm + qm * 64 + i * 16 + quad * 4;
            int b = m0 >> 11, s0_ = m0 & 2047;
            int kt = s0_ >> 6, sl = s0_ & 63;
            int ch = sl >> 3, off = sl & 7, key = d & 15;
            ushort4 h4, l4;
            splitbf(acc[qm][qn][i][j][0] + bn, h4.x, l4.x);
            splitbf(acc[qm][qn][i][j][1] + bn, h4.y, l4.y);
            splitbf(acc[qm][qn][i][j][2] + bn, h4.z, l4.z);
            splitbf(acc[qm][qn][i][j][3] + bn, h4.w, l4.w);
            size_t base =
                (size_t)(b * NH + h) * 262144 + (size_t)d * 4096 + kt * 128;
            *(ushort4*)(vt + base + ((ch ^ key)) * 8 + off) = h4;
            *(ushort4*)(vt + base + (((ch + 8) ^ key)) * 8 + off) = l4;
          }
  }
}

// ---------------------------------------------------------------------------
// Single-barrier dbuf output GEMM (unchanged).
// ---------------------------------------------------------------------------
__global__ __launch_bounds__(256)
void out_gemm(const unsigned short* __restrict__ a_all,
              const unsigned short* __restrict__ Wot,
              const float* __restrict__ bo, float* __restrict__ out) {
  const int ntile = blockIdx.x, mt = blockIdx.y;

  __shared__ alignas(16) unsigned short As[2][64 * 64];
  __shared__ alignas(16) unsigned short Bs[2][128 * 64];

  const int tid = threadIdx.x;
  const int lane = tid & 63, w = tid >> 6;
  const int l15 = lane & 15, quad = lane >> 4;
  const int wn = w * 32;
  const int kx = l15 & 7;

  const unsigned short* Ap = a_all + (size_t)(mt * 64) * 2048;
  const unsigned short* Bp = Wot + (size_t)(ntile * 128) * 2048;

#pragma unroll
  for (int it = 0; it < 2; ++it) {
    int s = tid + it * 256;
    int r = s >> 3, seg = s & 7;
    gld16(Ap + (size_t)r * 2048 + seg * 8, &As[0][s * 8]);
  }
#pragma unroll
  for (int it = 0; it < 4; ++it) {
    int s = tid + it * 256;
    int r = s >> 3, seg = s & 7;
    gld16(Bp + (size_t)r * 2048 + seg * 8, &Bs[0][s * 8]);
  }

  f32x4 acc[4][2];
#pragma unroll
  for (int i = 0; i < 4; ++i)
#pragma unroll
    for (int j = 0; j < 2; ++j) acc[i][j] = (f32x4){0.f, 0.f, 0.f, 0.f};

  int cur = 0;
  for (int kk = 0; kk < 32; ++kk) {
    __syncthreads();

    if (kk + 1 < 32) {
      int blk = (kk + 1) * 64;
#pragma unroll
      for (int it = 0; it < 2; ++it) {
        int s = tid + it * 256;
        int r = s >> 3, seg = s & 7;
        gld16(Ap + (size_t)r * 2048 + blk + seg * 8, &As[cur ^ 1][s * 8]);
      }
#pragma unroll
      for (int it = 0; it < 4; ++it) {
        int s = tid + it * 256;
        int r = s >> 3, seg = s & 7;
        gld16(Bp + (size_t)r * 2048 + blk + seg * 8, &Bs[cur ^ 1][s * 8]);
      }
    }

    bf16x8 ah[4], al[4];
#pragma unroll
    for (int i = 0; i < 4; ++i) {
      const unsigned short* p = &As[cur][(i * 16 + l15) * 64];
      ah[i] = *(const bf16x8*)(p + ((quad ^ kx)) * 8);
      al[i] = *(const bf16x8*)(p + (((quad + 4) ^ kx)) * 8);
    }
#pragma unroll
    for (int j = 0; j < 2; ++j) {
      const unsigned short* p = &Bs[cur][(wn + j * 16 + l15) * 64];
      bf16x8 bh = *(const bf16x8*)(p + ((quad ^ kx)) * 8);
      bf16x8 bl = *(const bf16x8*)(p + (((quad + 4) ^ kx)) * 8);
#pragma unroll
      for (int i = 0; i < 4; ++i) {
        acc[i][j] = __builtin_amdgcn_mfma_f32_16x16x32_bf16(ah[i], bh, acc[i][j], 0, 0, 0);
        acc[i][j] = __builtin_amdgcn_mfma_f32_16x16x32_bf16(al[i], bh, acc[i][j], 0, 0, 0);
        acc[i][j] = __builtin_amdgcn_mfma_f32_16x16x32_bf16(ah[i], bl, acc[i][j], 0, 0, 0);
      }
    }
    cur ^= 1;
  }

#pragma unroll
  for (int i = 0; i < 4; ++i)
#pragma unroll
    for (int j = 0; j < 2; ++j) {
      int n = ntile * 128 + wn + j * 16 + l15;
      float bn = bo[n];
#pragma unroll
      for (int r = 0; r < 4; ++r) {
        int m = mt * 64 + i * 16 + quad * 4 + r;
        out[(size_t)m * DM + n] = acc[i][j][r] + bn;
      }
    }
}

// ---------------------------------------------------------------------------
// MFMA flash attention, R2 geometry (KVBLK=64, QBLK=128, 80 KB, 2 blocks/CU)
// with SWAPPED QK^T (mfma(K,Q)): each lane's sc holds one q-row (l15) and 4
// consecutive k (quad*4+r) per ct-tile. P converts via 2x v_cvt_pk_bf16_f32
// (RNE, bit-identical to f2bf) and stores with ONE ds_write_b64 per (rt,ct):
// 8 b64 writes + 16 cvt_pk replace 32 b16 writes + ~128 VALU. Written memory
// image is byte-identical to R2's Ps (chunk ct*2+(quad>>1), key (l15>>1)&7,
// off (quad&1)*4), so the proven PV read path is untouched. lpart becomes a
// per-lane sum over its 16 k; reduce across quads (shfl_xor 16/32), then 4
// bpermutes map inv back to C-layout rows. Wave-private Ps (no P barriers),
// 1 staging barrier/tile, setprio around MFMA clusters.
// ---------------------------------------------------------------------------
__global__ __launch_bounds__(256)
void attn_kernel(const unsigned short* __restrict__ q_all,
                 const unsigned short* __restrict__ k_all,
                 const unsigned short* __restrict__ vt,
                 unsigned short* __restrict__ a_all) {
  const int qt = blockIdx.x, h = blockIdx.y, b = blockIdx.z;
  const unsigned short* vp = vt + (size_t)(b * NH + h) * 262144;

  __shared__ alignas(16) unsigned short Ks[2][64 * 128];
  __shared__ alignas(16) unsigned short Vs[2][64 * 128];
  __shared__ alignas(16) unsigned short Ps[128 * 64];

  const int tid = threadIdx.x;
  const int lane = tid & 63;
  const int w = tid >> 6;
  const int l15 = lane & 15;
  const int quad = lane >> 4;

  bf16x8 qf[2][2][2];
#pragma unroll
  for (int rt = 0; rt < 2; ++rt) {
    const unsigned short* qrow =
        q_all + (size_t)(b * SLEN + qt * 128 + w * 32 + rt * 16 + l15) * 2048 +
        h * 128;
#pragma unroll
    for (int kb = 0; kb < 2; ++kb) {
      qf[rt][kb][0] = *(const bf16x8*)(qrow + ((kb * 8 + quad) ^ l15) * 8);
      qf[rt][kb][1] = *(const bf16x8*)(qrow + ((kb * 8 + quad + 4) ^ l15) * 8);
    }
  }

  // prologue: stage kt=0
  {
    const unsigned short* ksrc = k_all + (size_t)(b * SLEN) * 2048 + h * 128;
#pragma unroll
    for (int it = 0; it < 4; ++it) {
      int ss = it * 256 + tid;
      int r = ss >> 4, p = ss & 15;
      gld16(ksrc + (size_t)r * 2048 + p * 8, &Ks[0][ss * 8]);
    }
#pragma unroll
    for (int it = 0; it < 4; ++it) {
      int ss = it * 256 + tid;
      int d = ss >> 4, p = ss & 15;
      gld16(vp + (size_t)d * 4096 + p * 8, &Vs[0][ss * 8]);
    }
  }

  f32x4 o[2][4];
  float lpart[2];
#pragma unroll
  for (int rt = 0; rt < 2; ++rt) {
    lpart[rt] = 0.f;
#pragma unroll
    for (int nt = 0; nt < 4; ++nt) o[rt][nt] = (f32x4){0.f, 0.f, 0.f, 0.f};
  }

  int cur = 0;
  for (int kt = 0; kt < STILES; ++kt) {
    __syncthreads();  // glds(kt) done (aged through prev iteration for kt>0)

    if (kt + 1 < STILES) {  // prefetch kt+1 into alt buffers
      const unsigned short* ksrc =
          k_all + (size_t)(b * SLEN + (kt + 1) * 64) * 2048 + h * 128;
#pragma unroll
      for (int it = 0; it < 4; ++it) {
        int ss = it * 256 + tid;
        int r = ss >> 4, p = ss & 15;
        gld16(ksrc + (size_t)r * 2048 + p * 8, &Ks[cur ^ 1][ss * 8]);
      }
#pragma unroll
      for (int it = 0; it < 4; ++it) {
        int ss = it * 256 + tid;
        int d = ss >> 4, p = ss & 15;
        gld16(vp + (size_t)d * 4096 + (kt + 1) * 128 + p * 8,
              &Vs[cur ^ 1][ss * 8]);
      }
    }

    // swapped QK^T: sc[rt][ct] C-layout = [row=k-pos][col=q-row]
    f32x4 sc[2][4];
#pragma unroll
    for (int rt = 0; rt < 2; ++rt)
#pragma unroll
      for (int ct = 0; ct < 4; ++ct) sc[rt][ct] = (f32x4){0.f, 0.f, 0.f, 0.f};
    __builtin_amdgcn_s_setprio(1);
#pragma unroll
    for (int ct = 0; ct < 4; ++ct) {
      const unsigned short* kbase = &Ks[cur][(ct * 16 + l15) * 128];
#pragma unroll
      for (int kb = 0; kb < 2; ++kb) {
        bf16x8 kh = *(const bf16x8*)(kbase + ((kb * 8 + quad) ^ l15) * 8);
        bf16x8 kl = *(const bf16x8*)(kbase + ((kb * 8 + quad + 4) ^ l15) * 8);
#pragma unroll
        for (int rt = 0; rt < 2; ++rt) {
          sc[rt][ct] = __builtin_amdgcn_mfma_f32_16x16x32_bf16(kh, qf[rt][kb][0], sc[rt][ct], 0, 0, 0);
          sc[rt][ct] = __builtin_amdgcn_mfma_f32_16x16x32_bf16(kl, qf[rt][kb][0], sc[rt][ct], 0, 0, 0);
          sc[rt][ct] = __builtin_amdgcn_mfma_f32_16x16x32_bf16(kh, qf[rt][kb][1], sc[rt][ct], 0, 0, 0);
        }
      }
    }
    __builtin_amdgcn_s_setprio(0);

    // softmax + packed P-write: lane owns q-row l15, k = ct*16 + quad*4 + r
#pragma unroll
    for (int rt = 0; rt < 2; ++rt) {
      const int prow = w * 32 + rt * 16 + l15;
      const int pk = (l15 >> 1) & 7;
      unsigned short* prowp = &Ps[prow * 64 + (quad & 1) * 4];
#pragma unroll
      for (int ct = 0; ct < 4; ++ct) {
        float e0 = __expf(sc[rt][ct][0] * 0.125f);
        float e1 = __expf(sc[rt][ct][1] * 0.125f);
        float e2 = __expf(sc[rt][ct][2] * 0.125f);
        float e3 = __expf(sc[rt][ct][3] * 0.125f);
        lpart[rt] += (e0 + e1) + (e2 + e3);
        unsigned plo, phi;
        asm("v_cvt_pk_bf16_f32 %0, %1, %2" : "=v"(plo) : "v"(e0), "v"(e1));
        asm("v_cvt_pk_bf16_f32 %0, %1, %2" : "=v"(phi) : "v"(e2), "v"(e3));
        uint2 pu;
        pu.x = plo;
        pu.y = phi;
        *(uint2*)(prowp + (((ct * 2 + (quad >> 1)) ^ pk)) * 8) = pu;
      }
    }
    // P is wave-private: same-wave DS order + lgkmcnt fence suffices.
    asm volatile("s_waitcnt lgkmcnt(0)" ::: "memory");
    __builtin_amdgcn_sched_barrier(0);

    int rk = (l15 >> 1) & 7;
#pragma unroll
    for (int kb = 0; kb < 2; ++kb) {
      bf16x8 pf[2];
#pragma unroll
      for (int rt = 0; rt < 2; ++rt)
        pf[rt] = *(const bf16x8*)(&Ps[(w * 32 + rt * 16 + l15) * 64 +
                                      (((kb * 4 + quad) ^ rk)) * 8]);
      __builtin_amdgcn_s_setprio(1);
#pragma unroll
      for (int nt = 0; nt < 4; ++nt) {
        const unsigned short* vb = &Vs[cur][(nt * 16 + l15) * 128];
        bf16x8 vh = *(const bf16x8*)(vb + (((kb * 4 + quad) ^ l15)) * 8);
        bf16x8 vl = *(const bf16x8*)(vb + (((kb * 4 + quad + 8) ^ l15)) * 8);
#pragma unroll
        for (int rt = 0; rt < 2; ++rt) {
          o[rt][nt] = __builtin_amdgcn_mfma_f32_16x16x32_bf16(pf[rt], vh, o[rt][nt], 0, 0, 0);
          o[rt][nt] = __builtin_amdgcn_mfma_f32_16x16x32_bf16(pf[rt], vl, o[rt][nt], 0, 0, 0);
        }
      }
      __builtin_amdgcn_s_setprio(0);
    }
    // pf reads complete before next iteration's P writes (same-wave order).
    cur ^= 1;
  }

#pragma unroll
  for (int rt = 0; rt < 2; ++rt) {
    // lpart: per-lane partial for q-row l15 over its 16 k per tile; total =
    // sum across the 4 quads.
    float lv = lpart[rt];
    lv += __shfl_xor(lv, 16, 64);
    lv += __shfl_xor(lv, 32, 64);
    float invv = 1.f / lv;  // q-row l15, replicated across quads
    float inv[4];
#pragma unroll
    for (int r = 0; r < 4; ++r) inv[r] = __shfl(invv, quad * 4 + r, 64);
#pragma unroll
    for (int nt = 0; nt < 4; ++nt) {
      int c = h * 64 + nt * 16 + l15;
      int Bb = c >> 5;
      int d32 = c & 31;
      int ch = d32 >> 3, off = d32 & 7;
#pragma unroll
      for (int r = 0; r < 4; ++r) {
        float val = o[rt][nt][r] * inv[r];
        int srow = qt * 128 + w * 32 + rt * 16 + quad * 4 + r;
        int key = srow & 7;
        size_t g = (size_t)(b * SLEN + srow) * 2048 + Bb * 64;
        unsigned short hv, lv2;
        splitbf(val, hv, lv2);
        a_all[g + ((ch ^ key)) * 8 + off] = hv;
        a_all[g + (((ch + 4) ^ key)) * 8 + off] = lv2;
      }
    }
  }
}

extern "C" void kernel_launch(void* const* d_in, const int* in_sizes, int n_in,
                              void* d_out, int out_size, void* d_ws,
                              size_t ws_size, hipStream_t stream) {
  (void)in_sizes; (void)n_in; (void)out_size; (void)ws_size;
  const float* Q = (const float*)d_in[0];
  const float* K = (const float*)d_in[1];
  const float* V = (const float*)d_in[2];
  const float* Wq = (const float*)d_in[3];
  const float* bq = (const float*)d_in[4];
  const float* Wk = (const float*)d_in[5];
  const float* bk = (const float*)d_in[6];
  const float* Wv = (const float*)d_in[7];
  const float* bv = (const float*)d_in[8];
  const float* Wo = (const float*)d_in[9];
  const float* bo = (const float*)d_in[10];
  float* out = (float*)d_out;

  // ws layout (u16 units), 112 MB total:
  //   q_all [0,8M)  k_all [8M,16M)  vt [16M,24M)
  //   a_all [24M,32M) -- Wqt/Wkt/Wvt overlaid (dead before attn writes a_all)
  //   Xp    [32M,56M) -- 3x 8M u16 packed split inputs (dead after proj)
  //   Wot overlays q_all (dead after attn)
  unsigned short* us = (unsigned short*)d_ws;
  const size_t M8 = 8u * 1024 * 1024;
  unsigned short* q_all = us;
  unsigned short* k_all = us + M8;
  unsigned short* vt = us + 2 * M8;
  unsigned short* a_all = us + 3 * M8;
  unsigned short* Wqt = a_all;
  unsigned short* Wkt = a_all + 2 * 1024 * 1024;
  unsigned short* Wvt = a_all + 4 * 1024 * 1024;
  unsigned short* Xp = us + 4 * M8;
  unsigned short* Wot = q_all;

  convert_w<<<dim3(16, 16, 3), 256, 0, stream>>>(Wq, Wk, Wv, Wqt, Wkt, Wvt);
  convert_x<<<dim3(4096, 3), 256, 0, stream>>>(Q, K, V, Xp);
  proj_gemm<<<dim3(4, 16, 3), 512, 0, stream>>>(Xp, Wqt, Wkt, Wvt, bq, bk, bv,
                                                q_all, k_all, vt);
  attn_kernel<<<dim3(SLEN / 128, NH, BATCH), 256, 0, stream>>>(q_all, k_all,
                                                               vt, a_all);
  convert_wo<<<dim3(1024), 256, 0, stream>>>(Wo, Wot);
  out_gemm<<<dim3(8, 64), 256, 0, stream>>>(a_all, Wot, bo, out);
}

// Round 6
// 332.867 us; speedup vs baseline: 1.1034x; 1.0200x over previous
//
#include <hip/hip_runtime.h>
#include <math.h>

#define BATCH 2
#define SLEN 2048
#define DM 1024
#define NH 16
#define DK 64
#define STILES (SLEN / 64)  // 32

typedef __attribute__((ext_vector_type(8))) __bf16 bf16x8;
typedef __attribute__((ext_vector_type(4))) float f32x4;

__device__ __forceinline__ unsigned short f2bf(float x) {  // round-nearest
  unsigned u = __builtin_bit_cast(unsigned, x);
  unsigned r = (u + 0x7fffu + ((u >> 16) & 1u)) >> 16;
  return (unsigned short)r;
}
// cheap truncation split: x ~= hi + lo to ~2^-16 relative
__device__ __forceinline__ void splitbf(float x, unsigned short& h,
                                        unsigned short& l) {
  unsigned u = __builtin_bit_cast(unsigned, x);
  h = (unsigned short)(u >> 16);
  float hf = __builtin_bit_cast(float, u & 0xffff0000u);
  l = (unsigned short)(__builtin_bit_cast(unsigned, x - hf) >> 16);
}

// async global->LDS, 16 B per lane
__device__ __forceinline__ void gld16(const unsigned short* g,
                                      unsigned short* l) {
  __builtin_amdgcn_global_load_lds(
      (const __attribute__((address_space(1))) void*)g,
      (__attribute__((address_space(3))) void*)l, 16, 0, 0);
}

// ---------------------------------------------------------------------------
// Weight transpose+split -> Wt[n][packed k], 64-u16 k-blocks [hi32|lo32],
// 16-B chunks XOR-swizzled with key (n&7).
// ---------------------------------------------------------------------------
__global__ __launch_bounds__(256)
void convert_w(const float* __restrict__ Wq, const float* __restrict__ Wk,
               const float* __restrict__ Wv, unsigned short* __restrict__ Wqt,
               unsigned short* __restrict__ Wkt,
               unsigned short* __restrict__ Wvt) {
  const int kb = blockIdx.x, h = blockIdx.y, z = blockIdx.z;
  const float* W = (z == 0 ? Wq : z == 1 ? Wk : Wv) +
                   ((size_t)h * DM + kb * 64) * DK;
  unsigned short* D = (z == 0 ? Wqt : z == 1 ? Wkt : Wvt);

  __shared__ float T[64][65];
  const int tid = threadIdx.x;
  {
    int r = tid >> 2, c0 = (tid & 3) * 16;
#pragma unroll
    for (int i = 0; i < 4; ++i) {
      float4 f = *(const float4*)(W + (size_t)r * DK + c0 + i * 4);
      T[r][c0 + i * 4 + 0] = f.x;
      T[r][c0 + i * 4 + 1] = f.y;
      T[r][c0 + i * 4 + 2] = f.z;
      T[r][c0 + i * 4 + 3] = f.w;
    }
  }
  __syncthreads();
  int j = tid >> 2, p = tid & 3;
  int n = h * 64 + j;
  int kloc = p * 16;
  unsigned short hi[16], lo[16];
#pragma unroll
  for (int i = 0; i < 16; ++i) splitbf(T[kloc + i][j], hi[i], lo[i]);
  int kglob = kb * 64 + kloc;
  int blk = kglob >> 5;
  int c0 = (kglob & 31) >> 3;
  int key = n & 7;
  unsigned short* rowp = D + (size_t)n * 2048 + blk * 64;
  uint4 u0, u1;
  u0.x = (unsigned)hi[0] | ((unsigned)hi[1] << 16);
  u0.y = (unsigned)hi[2] | ((unsigned)hi[3] << 16);
  u0.z = (unsigned)hi[4] | ((unsigned)hi[5] << 16);
  u0.w = (unsigned)hi[6] | ((unsigned)hi[7] << 16);
  u1.x = (unsigned)hi[8] | ((unsigned)hi[9] << 16);
  u1.y = (unsigned)hi[10] | ((unsigned)hi[11] << 16);
  u1.z = (unsigned)hi[12] | ((unsigned)hi[13] << 16);
  u1.w = (unsigned)hi[14] | ((unsigned)hi[15] << 16);
  *(uint4*)(rowp + ((c0 ^ key)) * 8) = u0;
  *(uint4*)(rowp + (((c0 + 1) ^ key)) * 8) = u1;
  u0.x = (unsigned)lo[0] | ((unsigned)lo[1] << 16);
  u0.y = (unsigned)lo[2] | ((unsigned)lo[3] << 16);
  u0.z = (unsigned)lo[4] | ((unsigned)lo[5] << 16);
  u0.w = (unsigned)lo[6] | ((unsigned)lo[7] << 16);
  u1.x = (unsigned)lo[8] | ((unsigned)lo[9] << 16);
  u1.y = (unsigned)lo[10] | ((unsigned)lo[11] << 16);
  u1.z = (unsigned)lo[12] | ((unsigned)lo[13] << 16);
  u1.w = (unsigned)lo[14] | ((unsigned)lo[15] << 16);
  *(uint4*)(rowp + (((c0 + 4) ^ key)) * 8) = u0;
  *(uint4*)(rowp + (((c0 + 5) ^ key)) * 8) = u1;
}

// ---------------------------------------------------------------------------
// X pre-split: X[m][k] fp32 -> Xp[z][m][packed k] (swizzle key m&7).
// grid (4096, 3), block 256.
// ---------------------------------------------------------------------------
__global__ __launch_bounds__(256)
void convert_x(const float* __restrict__ Q, const float* __restrict__ K,
               const float* __restrict__ V, unsigned short* __restrict__ Xp) {
  const int m = blockIdx.x, z = blockIdx.y;
  const float* src = (z == 0 ? Q : z == 1 ? K : V) + (size_t)m * DM;
  unsigned short* dst =
      Xp + (size_t)z * (8u * 1024 * 1024) + (size_t)m * 2048;
  const int k0 = threadIdx.x * 4;
  float4 f = *(const float4*)(src + k0);
  ushort4 h4, l4;
  splitbf(f.x, h4.x, l4.x);
  splitbf(f.y, h4.y, l4.y);
  splitbf(f.z, h4.z, l4.z);
  splitbf(f.w, h4.w, l4.w);
  int blk = k0 >> 5, ch = (k0 & 31) >> 3, off = k0 & 7, key = m & 7;
  unsigned short* rowp = dst + blk * 64;
  *(ushort4*)(rowp + ((ch ^ key)) * 8 + off) = h4;
  *(ushort4*)(rowp + (((ch + 4) ^ key)) * 8 + off) = l4;
}

// ---------------------------------------------------------------------------
// Wo pre-split: Wo[n][k] fp32 -> Wot[n][packed k] (swizzled like Wt).
// Runs AFTER attn (q_all region dead). grid 1024, block 256.
// ---------------------------------------------------------------------------
__global__ __launch_bounds__(256)
void convert_wo(const float* __restrict__ Wo, unsigned short* __restrict__ Wot) {
  const int n = blockIdx.x;
  const int t = threadIdx.x;
  const int k0 = t * 4;
  float4 f = *(const float4*)(Wo + (size_t)n * DM + k0);
  ushort4 h4, l4;
  splitbf(f.x, h4.x, l4.x);
  splitbf(f.y, h4.y, l4.y);
  splitbf(f.z, h4.z, l4.z);
  splitbf(f.w, h4.w, l4.w);
  int blk = k0 >> 5, ch = (k0 & 31) >> 3, off = k0 & 7, key = n & 7;
  unsigned short* rowp = Wot + (size_t)n * 2048 + blk * 64;
  *(ushort4*)(rowp + ((ch ^ key)) * 8 + off) = h4;
  *(ushort4*)(rowp + (((ch + 4) ^ key)) * 8 + off) = l4;
}

// ---------------------------------------------------------------------------
// 256x256 proj GEMM, 4-phase schedule: phase = (buffer, QM) covering the
// full 64-col wave extent. A-frags (8 ds_reads) loaded once per phase and
// reused across both QN halves; B read in two 4-read clusters (QN0 with A,
// QN1 mid-phase after the QN0 MFMA cluster -- sched_barrier(0) pins the
// order so the allocator reuses the dead B regs). vs the 8-phase version:
// barriers/iter 16->8, ds_reads/iter 96->64 (-33%), MFMA unchanged (48 per
// phase). vmcnt ledger: invariant 4 outstanding at iter top; VMW(4) at ph2
// and ph4 drains exactly the tile needed by the next two phases; tail iter
// VMW(0) at ph2. Same-buffer stage-vs-read: previous-phase reads are sealed
// by lgkm(0)+barrier; same-phase overwrites only touch halves whose reads
// were issued earlier in the phase (B-half0) or not read (disjoint halves);
// mid-phase QN1 reads touch only B-half1, staging only B-half0.
// ---------------------------------------------------------------------------
__global__ __launch_bounds__(512, 2)
void proj_gemm(const unsigned short* __restrict__ Xp,
               const unsigned short* __restrict__ Wqt,
               const unsigned short* __restrict__ Wkt,
               const unsigned short* __restrict__ Wvt,
               const float* __restrict__ bq, const float* __restrict__ bk,
               const float* __restrict__ bv, unsigned short* __restrict__ q_all,
               unsigned short* __restrict__ k_all,
               unsigned short* __restrict__ vt) {
  const int ntile = blockIdx.x, mt = blockIdx.y, z = blockIdx.z;
  const unsigned short* Bw = (z == 0 ? Wqt : z == 1 ? Wkt : Wvt);
  const float* bias = (z == 0 ? bq : z == 1 ? bk : bv);

  __shared__ alignas(16) unsigned short As[2][256 * 64];
  __shared__ alignas(16) unsigned short Bs[2][256 * 64];

  const int tid = threadIdx.x;
  const int lane = tid & 63, w = tid >> 6;
  const int l15 = lane & 15, quad = lane >> 4;
  const int wm = (w >> 2) * 128, wn = (w & 3) * 64;
  const int kx = l15 & 7;
  const int r0 = tid >> 3, seg = tid & 7;  // staging: 1024 16B-chunks/half

  const unsigned short* Ap =
      Xp + (size_t)z * (8u * 1024 * 1024) + (size_t)(mt * 256) * 2048;
  const unsigned short* Bp = Bw + (size_t)(ntile * 256) * 2048;

  // A-half hh: rows hh*64 + r0 and 128 + hh*64 + r0   (r0 in [0,64))
#define STAGE_A(bf, hh, t)                                                    \
  do {                                                                        \
    const unsigned short* _s =                                                \
        Ap + (size_t)((hh)*64 + r0) * 2048 + (t)*64 + seg * 8;                \
    unsigned short* _d = &As[bf][((hh)*64 + r0) * 64 + seg * 8];              \
    gld16(_s, _d);                                                            \
    gld16(_s + (size_t)128 * 2048, _d + 128 * 64);                            \
  } while (0)
  // B-half hh: rows ((r0>>5)<<6) + hh*32 + (r0&31), and +128
#define STAGE_B(bf, hh, t)                                                    \
  do {                                                                        \
    int _rb = ((r0 >> 5) << 6) + (hh)*32 + (r0 & 31);                         \
    const unsigned short* _s = Bp + (size_t)_rb * 2048 + (t)*64 + seg * 8;    \
    unsigned short* _d = &Bs[bf][_rb * 64 + seg * 8];                         \
    gld16(_s, _d);                                                            \
    gld16(_s + (size_t)128 * 2048, _d + 128 * 64);                            \
  } while (0)
#define VMW(n) asm volatile("s_waitcnt vmcnt(" #n ")" ::: "memory")

  // phase = (BUF, QM): A-half QM frags once, B in two QN clusters.
#define PHASE4(BUF, QM, STG, VMS)                                             \
  do {                                                                        \
    bf16x8 ah_[4], al_[4];                                                    \
    _Pragma("unroll") for (int i_ = 0; i_ < 4; ++i_) {                        \
      const unsigned short* p_ =                                              \
          &As[BUF][(wm + (QM)*64 + i_ * 16 + l15) * 64];                      \
      ah_[i_] = *(const bf16x8*)(p_ + ((quad ^ kx)) * 8);                     \
      al_[i_] = *(const bf16x8*)(p_ + (((quad + 4) ^ kx)) * 8);               \
    }                                                                         \
    bf16x8 bh_[2], bl_[2];                                                    \
    _Pragma("unroll") for (int j_ = 0; j_ < 2; ++j_) {                        \
      const unsigned short* p_ = &Bs[BUF][(wn + j_ * 16 + l15) * 64];         \
      bh_[j_] = *(const bf16x8*)(p_ + ((quad ^ kx)) * 8);                     \
      bl_[j_] = *(const bf16x8*)(p_ + (((quad + 4) ^ kx)) * 8);               \
    }                                                                         \
    STG;                                                                      \
    VMS;                                                                      \
    asm volatile("s_waitcnt lgkmcnt(8)" ::: "memory");                        \
    __builtin_amdgcn_s_barrier();                                             \
    asm volatile("s_waitcnt lgkmcnt(0)" ::: "memory");                        \
    __builtin_amdgcn_sched_barrier(0);                                        \
    __builtin_amdgcn_s_setprio(1);                                            \
    _Pragma("unroll") for (int j_ = 0; j_ < 2; ++j_)                          \
        _Pragma("unroll") for (int i_ = 0; i_ < 4; ++i_) {                    \
      acc[QM][0][i_][j_] = __builtin_amdgcn_mfma_f32_16x16x32_bf16(           \
          ah_[i_], bh_[j_], acc[QM][0][i_][j_], 0, 0, 0);                     \
      acc[QM][0][i_][j_] = __builtin_amdgcn_mfma_f32_16x16x32_bf16(           \
          al_[i_], bh_[j_], acc[QM][0][i_][j_], 0, 0, 0);                     \
      acc[QM][0][i_][j_] = __builtin_amdgcn_mfma_f32_16x16x32_bf16(           \
          ah_[i_], bl_[j_], acc[QM][0][i_][j_], 0, 0, 0);                     \
    }                                                                         \
    __builtin_amdgcn_sched_barrier(0);                                        \
    bf16x8 bh2_[2], bl2_[2];                                                  \
    _Pragma("unroll") for (int j_ = 0; j_ < 2; ++j_) {                        \
      const unsigned short* p_ = &Bs[BUF][(wn + 32 + j_ * 16 + l15) * 64];    \
      bh2_[j_] = *(const bf16x8*)(p_ + ((quad ^ kx)) * 8);                    \
      bl2_[j_] = *(const bf16x8*)(p_ + (((quad + 4) ^ kx)) * 8);              \
    }                                                                         \
    asm volatile("s_waitcnt lgkmcnt(0)" ::: "memory");                        \
    __builtin_amdgcn_sched_barrier(0);                                        \
    _Pragma("unroll") for (int j_ = 0; j_ < 2; ++j_)                          \
        _Pragma("unroll") for (int i_ = 0; i_ < 4; ++i_) {                    \
      acc[QM][1][i_][j_] = __builtin_amdgcn_mfma_f32_16x16x32_bf16(           \
          ah_[i_], bh2_[j_], acc[QM][1][i_][j_], 0, 0, 0);                    \
      acc[QM][1][i_][j_] = __builtin_amdgcn_mfma_f32_16x16x32_bf16(           \
          al_[i_], bh2_[j_], acc[QM][1][i_][j_], 0, 0, 0);                    \
      acc[QM][1][i_][j_] = __builtin_amdgcn_mfma_f32_16x16x32_bf16(           \
          ah_[i_], bl2_[j_], acc[QM][1][i_][j_], 0, 0, 0);                    \
    }                                                                         \
    __builtin_amdgcn_s_setprio(0);                                            \
    __builtin_amdgcn_sched_barrier(0);                                        \
    __builtin_amdgcn_s_barrier();                                             \
  } while (0)

  f32x4 acc[2][2][4][2];
#pragma unroll
  for (int a0 = 0; a0 < 2; ++a0)
#pragma unroll
    for (int a1 = 0; a1 < 2; ++a1)
#pragma unroll
      for (int a2 = 0; a2 < 4; ++a2)
#pragma unroll
        for (int a3 = 0; a3 < 2; ++a3)
          acc[a0][a1][a2][a3] = (f32x4){0.f, 0.f, 0.f, 0.f};

  // prologue: tile0 fully, then tile1 {B0, A0}; vmcnt(4) lands tile0.
  STAGE_B(0, 0, 0);
  STAGE_A(0, 0, 0);
  STAGE_A(0, 1, 0);
  STAGE_B(0, 1, 0);
  STAGE_B(1, 0, 1);
  STAGE_A(1, 0, 1);
  VMW(4);
  __builtin_amdgcn_s_barrier();

#pragma unroll 1
  for (int it2 = 0; it2 < 16; ++it2) {
    const int O = 2 * it2 + 1;        // odd K-step (buf1, phases 3-4)
    const int En = 2 * it2 + 2;       // next even K-step -> buf0
    const int On = 2 * it2 + 3;       // next odd K-step -> buf1
    const bool sE = (it2 < 15);
    PHASE4(0, 0, { STAGE_A(1, 1, O); STAGE_B(1, 1, O); }, (void)0);
    PHASE4(0, 1,
           if (sE) { STAGE_B(0, 0, En); STAGE_A(0, 0, En); },
           if (sE) { VMW(4); } else { VMW(0); });
    PHASE4(1, 0, if (sE) { STAGE_A(0, 1, En); STAGE_B(0, 1, En); }, (void)0);
    PHASE4(1, 1, if (sE) { STAGE_B(1, 0, On); STAGE_A(1, 0, On); },
           if (sE) VMW(4));
  }
#undef PHASE4
#undef VMW
#undef STAGE_A
#undef STAGE_B

  if (z <= 1) {
    unsigned short* dst = (z == 0 ? q_all : k_all);
#pragma unroll
    for (int qm = 0; qm < 2; ++qm)
#pragma unroll
      for (int qn = 0; qn < 2; ++qn)
#pragma unroll
        for (int i = 0; i < 4; ++i)
#pragma unroll
          for (int j = 0; j < 2; ++j) {
            int n = ntile * 256 + wn + qn * 32 + j * 16 + l15;
            int hh_ = n >> 6, d = n & 63;
            int chi = (d >> 5) * 8 + ((d & 31) >> 3);
            float bn = bias[n];
#pragma unroll
            for (int r = 0; r < 4; ++r) {
              int m = mt * 256 + wm + qm * 64 + i * 16 + quad * 4 + r;
              int key = m & 15;
              size_t rb = (size_t)m * 2048 + hh_ * 128;
              unsigned short hv, lv;
              splitbf(acc[qm][qn][i][j][r] + bn, hv, lv);
              dst[rb + ((chi ^ key)) * 8 + (d & 7)] = hv;
              dst[rb + (((chi + 4) ^ key)) * 8 + (d & 7)] = lv;
            }
          }
  } else {
#pragma unroll
    for (int qm = 0; qm < 2; ++qm)
#pragma unroll
      for (int qn = 0; qn < 2; ++qn)
#pragma unroll
        for (int i = 0; i < 4; ++i)
#pragma unroll
          for (int j = 0; j < 2; ++j) {
            int n = ntile * 256 + wn + qn * 32 + j * 16 + l15;
            int h = n >> 6, d = n & 63;
            float bn = bias[n];
            int m0 = mt * 256 + wm + qm * 64 + i * 16 + quad * 4;
            int b = m0 >> 11, s0_ = m0 & 2047;
            int kt = s0_ >> 6, sl = s0_ & 63;
            int ch = sl >> 3, off = sl & 7, key = d & 15;
            ushort4 h4, l4;
            splitbf(acc[qm][qn][i][j][0] + bn, h4.x, l4.x);
            splitbf(acc[qm][qn][i][j][1] + bn, h4.y, l4.y);
            splitbf(acc[qm][qn][i][j][2] + bn, h4.z, l4.z);
            splitbf(acc[qm][qn][i][j][3] + bn, h4.w, l4.w);
            size_t base =
                (size_t)(b * NH + h) * 262144 + (size_t)d * 4096 + kt * 128;
            *(ushort4*)(vt + base + ((ch ^ key)) * 8 + off) = h4;
            *(ushort4*)(vt + base + (((ch + 8) ^ key)) * 8 + off) = l4;
          }
  }
}

// ---------------------------------------------------------------------------
// Single-barrier dbuf output GEMM (unchanged).
// ---------------------------------------------------------------------------
__global__ __launch_bounds__(256)
void out_gemm(const unsigned short* __restrict__ a_all,
              const unsigned short* __restrict__ Wot,
              const float* __restrict__ bo, float* __restrict__ out) {
  const int ntile = blockIdx.x, mt = blockIdx.y;

  __shared__ alignas(16) unsigned short As[2][64 * 64];
  __shared__ alignas(16) unsigned short Bs[2][128 * 64];

  const int tid = threadIdx.x;
  const int lane = tid & 63, w = tid >> 6;
  const int l15 = lane & 15, quad = lane >> 4;
  const int wn = w * 32;
  const int kx = l15 & 7;

  const unsigned short* Ap = a_all + (size_t)(mt * 64) * 2048;
  const unsigned short* Bp = Wot + (size_t)(ntile * 128) * 2048;

#pragma unroll
  for (int it = 0; it < 2; ++it) {
    int s = tid + it * 256;
    int r = s >> 3, seg = s & 7;
    gld16(Ap + (size_t)r * 2048 + seg * 8, &As[0][s * 8]);
  }
#pragma unroll
  for (int it = 0; it < 4; ++it) {
    int s = tid + it * 256;
    int r = s >> 3, seg = s & 7;
    gld16(Bp + (size_t)r * 2048 + seg * 8, &Bs[0][s * 8]);
  }

  f32x4 acc[4][2];
#pragma unroll
  for (int i = 0; i < 4; ++i)
#pragma unroll
    for (int j = 0; j < 2; ++j) acc[i][j] = (f32x4){0.f, 0.f, 0.f, 0.f};

  int cur = 0;
  for (int kk = 0; kk < 32; ++kk) {
    __syncthreads();

    if (kk + 1 < 32) {
      int blk = (kk + 1) * 64;
#pragma unroll
      for (int it = 0; it < 2; ++it) {
        int s = tid + it * 256;
        int r = s >> 3, seg = s & 7;
        gld16(Ap + (size_t)r * 2048 + blk + seg * 8, &As[cur ^ 1][s * 8]);
      }
#pragma unroll
      for (int it = 0; it < 4; ++it) {
        int s = tid + it * 256;
        int r = s >> 3, seg = s & 7;
        gld16(Bp + (size_t)r * 2048 + blk + seg * 8, &Bs[cur ^ 1][s * 8]);
      }
    }

    bf16x8 ah[4], al[4];
#pragma unroll
    for (int i = 0; i < 4; ++i) {
      const unsigned short* p = &As[cur][(i * 16 + l15) * 64];
      ah[i] = *(const bf16x8*)(p + ((quad ^ kx)) * 8);
      al[i] = *(const bf16x8*)(p + (((quad + 4) ^ kx)) * 8);
    }
#pragma unroll
    for (int j = 0; j < 2; ++j) {
      const unsigned short* p = &Bs[cur][(wn + j * 16 + l15) * 64];
      bf16x8 bh = *(const bf16x8*)(p + ((quad ^ kx)) * 8);
      bf16x8 bl = *(const bf16x8*)(p + (((quad + 4) ^ kx)) * 8);
#pragma unroll
      for (int i = 0; i < 4; ++i) {
        acc[i][j] = __builtin_amdgcn_mfma_f32_16x16x32_bf16(ah[i], bh, acc[i][j], 0, 0, 0);
        acc[i][j] = __builtin_amdgcn_mfma_f32_16x16x32_bf16(al[i], bh, acc[i][j], 0, 0, 0);
        acc[i][j] = __builtin_amdgcn_mfma_f32_16x16x32_bf16(ah[i], bl, acc[i][j], 0, 0, 0);
      }
    }
    cur ^= 1;
  }

#pragma unroll
  for (int i = 0; i < 4; ++i)
#pragma unroll
    for (int j = 0; j < 2; ++j) {
      int n = ntile * 128 + wn + j * 16 + l15;
      float bn = bo[n];
#pragma unroll
      for (int r = 0; r < 4; ++r) {
        int m = mt * 64 + i * 16 + quad * 4 + r;
        out[(size_t)m * DM + n] = acc[i][j][r] + bn;
      }
    }
}

// ---------------------------------------------------------------------------
// MFMA flash attention with swapped QK^T + packed P-writes (unchanged from
// the passing R4 version).
// ---------------------------------------------------------------------------
__global__ __launch_bounds__(256)
void attn_kernel(const unsigned short* __restrict__ q_all,
                 const unsigned short* __restrict__ k_all,
                 const unsigned short* __restrict__ vt,
                 unsigned short* __restrict__ a_all) {
  const int qt = blockIdx.x, h = blockIdx.y, b = blockIdx.z;
  const unsigned short* vp = vt + (size_t)(b * NH + h) * 262144;

  __shared__ alignas(16) unsigned short Ks[2][64 * 128];
  __shared__ alignas(16) unsigned short Vs[2][64 * 128];
  __shared__ alignas(16) unsigned short Ps[128 * 64];

  const int tid = threadIdx.x;
  const int lane = tid & 63;
  const int w = tid >> 6;
  const int l15 = lane & 15;
  const int quad = lane >> 4;

  bf16x8 qf[2][2][2];
#pragma unroll
  for (int rt = 0; rt < 2; ++rt) {
    const unsigned short* qrow =
        q_all + (size_t)(b * SLEN + qt * 128 + w * 32 + rt * 16 + l15) * 2048 +
        h * 128;
#pragma unroll
    for (int kb = 0; kb < 2; ++kb) {
      qf[rt][kb][0] = *(const bf16x8*)(qrow + ((kb * 8 + quad) ^ l15) * 8);
      qf[rt][kb][1] = *(const bf16x8*)(qrow + ((kb * 8 + quad + 4) ^ l15) * 8);
    }
  }

  // prologue: stage kt=0
  {
    const unsigned short* ksrc = k_all + (size_t)(b * SLEN) * 2048 + h * 128;
#pragma unroll
    for (int it = 0; it < 4; ++it) {
      int ss = it * 256 + tid;
      int r = ss >> 4, p = ss & 15;
      gld16(ksrc + (size_t)r * 2048 + p * 8, &Ks[0][ss * 8]);
    }
#pragma unroll
    for (int it = 0; it < 4; ++it) {
      int ss = it * 256 + tid;
      int d = ss >> 4, p = ss & 15;
      gld16(vp + (size_t)d * 4096 + p * 8, &Vs[0][ss * 8]);
    }
  }

  f32x4 o[2][4];
  float lpart[2];
#pragma unroll
  for (int rt = 0; rt < 2; ++rt) {
    lpart[rt] = 0.f;
#pragma unroll
    for (int nt = 0; nt < 4; ++nt) o[rt][nt] = (f32x4){0.f, 0.f, 0.f, 0.f};
  }

  int cur = 0;
  for (int kt = 0; kt < STILES; ++kt) {
    __syncthreads();  // glds(kt) done (aged through prev iteration for kt>0)

    if (kt + 1 < STILES) {  // prefetch kt+1 into alt buffers
      const unsigned short* ksrc =
          k_all + (size_t)(b * SLEN + (kt + 1) * 64) * 2048 + h * 128;
#pragma unroll
      for (int it = 0; it < 4; ++it) {
        int ss = it * 256 + tid;
        int r = ss >> 4, p = ss & 15;
        gld16(ksrc + (size_t)r * 2048 + p * 8, &Ks[cur ^ 1][ss * 8]);
      }
#pragma unroll
      for (int it = 0; it < 4; ++it) {
        int ss = it * 256 + tid;
        int d = ss >> 4, p = ss & 15;
        gld16(vp + (size_t)d * 4096 + (kt + 1) * 128 + p * 8,
              &Vs[cur ^ 1][ss * 8]);
      }
    }

    // swapped QK^T: sc[rt][ct] C-layout = [row=k-pos][col=q-row]
    f32x4 sc[2][4];
#pragma unroll
    for (int rt = 0; rt < 2; ++rt)
#pragma unroll
      for (int ct = 0; ct < 4; ++ct) sc[rt][ct] = (f32x4){0.f, 0.f, 0.f, 0.f};
    __builtin_amdgcn_s_setprio(1);
#pragma unroll
    for (int ct = 0; ct < 4; ++ct) {
      const unsigned short* kbase = &Ks[cur][(ct * 16 + l15) * 128];
#pragma unroll
      for (int kb = 0; kb < 2; ++kb) {
        bf16x8 kh = *(const bf16x8*)(kbase + ((kb * 8 + quad) ^ l15) * 8);
        bf16x8 kl = *(const bf16x8*)(kbase + ((kb * 8 + quad + 4) ^ l15) * 8);
#pragma unroll
        for (int rt = 0; rt < 2; ++rt) {
          sc[rt][ct] = __builtin_amdgcn_mfma_f32_16x16x32_bf16(kh, qf[rt][kb][0], sc[rt][ct], 0, 0, 0);
          sc[rt][ct] = __builtin_amdgcn_mfma_f32_16x16x32_bf16(kl, qf[rt][kb][0], sc[rt][ct], 0, 0, 0);
          sc[rt][ct] = __builtin_amdgcn_mfma_f32_16x16x32_bf16(kh, qf[rt][kb][1], sc[rt][ct], 0, 0, 0);
        }
      }
    }
    __builtin_amdgcn_s_setprio(0);

    // softmax + packed P-write: lane owns q-row l15, k = ct*16 + quad*4 + r
#pragma unroll
    for (int rt = 0; rt < 2; ++rt) {
      const int prow = w * 32 + rt * 16 + l15;
      const int pk = (l15 >> 1) & 7;
      unsigned short* prowp = &Ps[prow * 64 + (quad & 1) * 4];
#pragma unroll
      for (int ct = 0; ct < 4; ++ct) {
        float e0 = __expf(sc[rt][ct][0] * 0.125f);
        float e1 = __expf(sc[rt][ct][1] * 0.125f);
        float e2 = __expf(sc[rt][ct][2] * 0.125f);
        float e3 = __expf(sc[rt][ct][3] * 0.125f);
        lpart[rt] += (e0 + e1) + (e2 + e3);
        unsigned plo, phi;
        asm("v_cvt_pk_bf16_f32 %0, %1, %2" : "=v"(plo) : "v"(e0), "v"(e1));
        asm("v_cvt_pk_bf16_f32 %0, %1, %2" : "=v"(phi) : "v"(e2), "v"(e3));
        uint2 pu;
        pu.x = plo;
        pu.y = phi;
        *(uint2*)(prowp + (((ct * 2 + (quad >> 1)) ^ pk)) * 8) = pu;
      }
    }
    // P is wave-private: same-wave DS order + lgkmcnt fence suffices.
    asm volatile("s_waitcnt lgkmcnt(0)" ::: "memory");
    __builtin_amdgcn_sched_barrier(0);

    int rk = (l15 >> 1) & 7;
#pragma unroll
    for (int kb = 0; kb < 2; ++kb) {
      bf16x8 pf[2];
#pragma unroll
      for (int rt = 0; rt < 2; ++rt)
        pf[rt] = *(const bf16x8*)(&Ps[(w * 32 + rt * 16 + l15) * 64 +
                                      (((kb * 4 + quad) ^ rk)) * 8]);
      __builtin_amdgcn_s_setprio(1);
#pragma unroll
      for (int nt = 0; nt < 4; ++nt) {
        const unsigned short* vb = &Vs[cur][(nt * 16 + l15) * 128];
        bf16x8 vh = *(const bf16x8*)(vb + (((kb * 4 + quad) ^ l15)) * 8);
        bf16x8 vl = *(const bf16x8*)(vb + (((kb * 4 + quad + 8) ^ l15)) * 8);
#pragma unroll
        for (int rt = 0; rt < 2; ++rt) {
          o[rt][nt] = __builtin_amdgcn_mfma_f32_16x16x32_bf16(pf[rt], vh, o[rt][nt], 0, 0, 0);
          o[rt][nt] = __builtin_amdgcn_mfma_f32_16x16x32_bf16(pf[rt], vl, o[rt][nt], 0, 0, 0);
        }
      }
      __builtin_amdgcn_s_setprio(0);
    }
    // pf reads complete before next iteration's P writes (same-wave order).
    cur ^= 1;
  }

#pragma unroll
  for (int rt = 0; rt < 2; ++rt) {
    float lv = lpart[rt];
    lv += __shfl_xor(lv, 16, 64);
    lv += __shfl_xor(lv, 32, 64);
    float invv = 1.f / lv;  // q-row l15, replicated across quads
    float inv[4];
#pragma unroll
    for (int r = 0; r < 4; ++r) inv[r] = __shfl(invv, quad * 4 + r, 64);
#pragma unroll
    for (int nt = 0; nt < 4; ++nt) {
      int c = h * 64 + nt * 16 + l15;
      int Bb = c >> 5;
      int d32 = c & 31;
      int ch = d32 >> 3, off = d32 & 7;
#pragma unroll
      for (int r = 0; r < 4; ++r) {
        float val = o[rt][nt][r] * inv[r];
        int srow = qt * 128 + w * 32 + rt * 16 + quad * 4 + r;
        int key = srow & 7;
        size_t g = (size_t)(b * SLEN + srow) * 2048 + Bb * 64;
        unsigned short hv, lv2;
        splitbf(val, hv, lv2);
        a_all[g + ((ch ^ key)) * 8 + off] = hv;
        a_all[g + (((ch + 4) ^ key)) * 8 + off] = lv2;
      }
    }
  }
}

extern "C" void kernel_launch(void* const* d_in, const int* in_sizes, int n_in,
                              void* d_out, int out_size, void* d_ws,
                              size_t ws_size, hipStream_t stream) {
  (void)in_sizes; (void)n_in; (void)out_size; (void)ws_size;
  const float* Q = (const float*)d_in[0];
  const float* K = (const float*)d_in[1];
  const float* V = (const float*)d_in[2];
  const float* Wq = (const float*)d_in[3];
  const float* bq = (const float*)d_in[4];
  const float* Wk = (const float*)d_in[5];
  const float* bk = (const float*)d_in[6];
  const float* Wv = (const float*)d_in[7];
  const float* bv = (const float*)d_in[8];
  const float* Wo = (const float*)d_in[9];
  const float* bo = (const float*)d_in[10];
  float* out = (float*)d_out;

  // ws layout (u16 units), 112 MB total:
  //   q_all [0,8M)  k_all [8M,16M)  vt [16M,24M)
  //   a_all [24M,32M) -- Wqt/Wkt/Wvt overlaid (dead before attn writes a_all)
  //   Xp    [32M,56M) -- 3x 8M u16 packed split inputs (dead after proj)
  //   Wot overlays q_all (dead after attn)
  unsigned short* us = (unsigned short*)d_ws;
  const size_t M8 = 8u * 1024 * 1024;
  unsigned short* q_all = us;
  unsigned short* k_all = us + M8;
  unsigned short* vt = us + 2 * M8;
  unsigned short* a_all = us + 3 * M8;
  unsigned short* Wqt = a_all;
  unsigned short* Wkt = a_all + 2 * 1024 * 1024;
  unsigned short* Wvt = a_all + 4 * 1024 * 1024;
  unsigned short* Xp = us + 4 * M8;
  unsigned short* Wot = q_all;

  convert_w<<<dim3(16, 16, 3), 256, 0, stream>>>(Wq, Wk, Wv, Wqt, Wkt, Wvt);
  convert_x<<<dim3(4096, 3), 256, 0, stream>>>(Q, K, V, Xp);
  proj_gemm<<<dim3(4, 16, 3), 512, 0, stream>>>(Xp, Wqt, Wkt, Wvt, bq, bk, bv,
                                                q_all, k_all, vt);
  attn_kernel<<<dim3(SLEN / 128, NH, BATCH), 256, 0, stream>>>(q_all, k_all,
                                                               vt, a_all);
  convert_wo<<<dim3(1024), 256, 0, stream>>>(Wo, Wot);
  out_gemm<<<dim3(8, 64), 256, 0, stream>>>(a_all, Wot, bo, out);
}